// Round 1
// baseline (1688.485 us; speedup 1.0000x reference)
//
#include <hip/hip_runtime.h>
#include <cstdint>
#include <cstddef>

// Problem constants (B,T,C,H,D) = (4,2048,1024,16,64)
#define Bz 4
#define Tz 2048
#define Cz 1024
#define Hz 16
#define Dz 64
#define NTOK (Bz*Tz)   // 8192 tokens

typedef __attribute__((ext_vector_type(8))) short  short8;   // 8 x bf16 (4 VGPRs)
typedef __attribute__((ext_vector_type(4))) float  floatx4;  // MFMA accum

__device__ __forceinline__ unsigned short f2bf(float x) {
  // round-to-nearest-even fp32 -> bf16
  union { float f; uint32_t u; } a; a.f = x;
  uint32_t r = a.u + 0x7fffu + ((a.u >> 16) & 1u);
  return (unsigned short)(r >> 16);
}

__device__ __forceinline__ float sigmoidf_(float z) {
  return 1.0f / (1.0f + __expf(-z));
}

// async global->LDS 16B; launder pointers through integers (low 32 bits of a
// flat LDS address are the LDS offset on gfx9+), avoids addrspace-cast errors.
__device__ __forceinline__ void gload_lds16(const void* gptr, void* lptr) {
  __builtin_amdgcn_global_load_lds(
      (const __attribute__((address_space(1))) void*)(uintptr_t)gptr,
      (__attribute__((address_space(3))) void*)(uint32_t)(uintptr_t)lptr,
      16, 0, 0);
}

// ---------------- fp32 -> bf16 convert ----------------
__global__ __launch_bounds__(256) void cvt_bf16_kernel(const float* __restrict__ in,
                                                       unsigned short* __restrict__ out,
                                                       int n4) {
  int i = blockIdx.x * blockDim.x + threadIdx.x;
  int stride = gridDim.x * blockDim.x;
  const float4* in4 = (const float4*)in;
  ushort4* out4 = (ushort4*)out;
  for (; i < n4; i += stride) {
    float4 f = in4[i];
    ushort4 u;
    u.x = f2bf(f.x); u.y = f2bf(f.y); u.z = f2bf(f.z); u.w = f2bf(f.w);
    out4[i] = u;
  }
}

// ---------------- bf16 MFMA GEMM: C[m,n] = sum_k A[m,k]*B[n,k]  (both K-contig) ---
// m97 structure: 128x128 tile, BK=32, 256 threads (4 waves 2x2), global_load_lds w=16.
// blockIdx.z selects one of 4 weight/output pairs (fused q,k,v,gate).
__global__ __launch_bounds__(256) void gemm_bt_kernel(
    const unsigned short* __restrict__ A,
    const unsigned short* __restrict__ W0, const unsigned short* __restrict__ W1,
    const unsigned short* __restrict__ W2, const unsigned short* __restrict__ W3,
    float* __restrict__ O0, float* __restrict__ O1,
    float* __restrict__ O2, float* __restrict__ O3,
    int M, int N, int K, int nz_sigmoid)
{
  const int z = blockIdx.z;
  const unsigned short* Bw = (z == 0) ? W0 : (z == 1) ? W1 : (z == 2) ? W2 : W3;
  float* Cw = (z == 0) ? O0 : (z == 1) ? O1 : (z == 2) ? O2 : O3;
  const bool act = (z == nz_sigmoid);

  __shared__ unsigned short As[128 * 32];  // 8 KB
  __shared__ unsigned short Bs[128 * 32];  // 8 KB

  const int tid  = threadIdx.x;
  const int wid  = tid >> 6;
  const int lane = tid & 63;
  const int wm = wid & 1, wn = wid >> 1;     // wave 64x64 quadrant
  const int m0 = blockIdx.y * 128;
  const int n0 = blockIdx.x * 128;

  const int srow = tid >> 2;          // staging row 0..63 (wave w covers rows w*16..)
  const int scol = (tid & 3) * 8;     // staging col in elements (8 bf16 = 16B)

  floatx4 acc[4][4];
#pragma unroll
  for (int i = 0; i < 4; ++i)
#pragma unroll
    for (int j = 0; j < 4; ++j)
      acc[i][j] = floatx4{0.f, 0.f, 0.f, 0.f};

  const int ml = lane & 15;   // MFMA row/col within 16
  const int kq = lane >> 4;   // k-quad

  const unsigned short* Arow0 = A  + (size_t)(m0 + srow) * K + scol;
  const unsigned short* Arow1 = A  + (size_t)(m0 + 64 + srow) * K + scol;
  const unsigned short* Brow0 = Bw + (size_t)(n0 + srow) * K + scol;
  const unsigned short* Brow1 = Bw + (size_t)(n0 + 64 + srow) * K + scol;

  for (int kt = 0; kt < K; kt += 32) {
    // stage: LDS dest = wave-uniform base + lane*16  (row-major 128x32, no pad)
    gload_lds16(Arow0 + kt, &As[wid * 512]);
    gload_lds16(Arow1 + kt, &As[2048 + wid * 512]);
    gload_lds16(Brow0 + kt, &Bs[wid * 512]);
    gload_lds16(Brow1 + kt, &Bs[2048 + wid * 512]);
    __syncthreads();  // drains vmcnt before any wave reads LDS

    short8 af[4], bfv[4];
#pragma unroll
    for (int i = 0; i < 4; ++i) {
      af[i]  = *(const short8*)&As[(wm * 64 + i * 16 + ml) * 32 + kq * 8];
      bfv[i] = *(const short8*)&Bs[(wn * 64 + i * 16 + ml) * 32 + kq * 8];
    }
#pragma unroll
    for (int i = 0; i < 4; ++i)
#pragma unroll
      for (int j = 0; j < 4; ++j)
        acc[i][j] = __builtin_amdgcn_mfma_f32_16x16x32_bf16(af[i], bfv[j], acc[i][j], 0, 0, 0);
    __syncthreads();
  }

  // epilogue: C/D layout col = lane&15, row = (lane>>4)*4 + reg  (m89/m91 verified)
  const int row_base = m0 + wm * 64;
  const int col_base = n0 + wn * 64;
#pragma unroll
  for (int i = 0; i < 4; ++i) {
#pragma unroll
    for (int j = 0; j < 4; ++j) {
      int col = col_base + j * 16 + ml;
#pragma unroll
      for (int r = 0; r < 4; ++r) {
        int row = row_base + i * 16 + kq * 4 + r;
        float val = acc[i][j][r];
        if (act) val = sigmoidf_(val);
        Cw[(size_t)row * N + col] = val;
      }
    }
  }
}

// ---------------- beta projection (fp32, exact): sigmoid(x @ Wbeta^T + b) ----------
__global__ __launch_bounds__(256) void beta_kernel(
    const float* __restrict__ x, const float* __restrict__ Wb,
    const float* __restrict__ bb, float* __restrict__ beta_out)
{
  const int n = blockIdx.x;           // token
  const int wid = threadIdx.x >> 6;
  const int lane = threadIdx.x & 63;
  const float* xr = x + (size_t)n * Cz;
  for (int h = wid; h < Hz; h += 4) {
    const float* wr = Wb + (size_t)h * Cz;
    float s = 0.f;
#pragma unroll 4
    for (int i = lane; i < Cz; i += 64) s = fmaf(xr[i], wr[i], s);
#pragma unroll
    for (int ofs = 32; ofs >= 1; ofs >>= 1) s += __shfl_xor(s, ofs);
    if (lane == 0) beta_out[(size_t)n * Hz + h] = sigmoidf_(s + bb[h]);
  }
}

// ---------------- delta-rule scan, row-parallel over M's rows ----------------------
// The recurrence is independent per row d of M: each single-wave block owns 4 rows
// (M in registers), no LDS, no barriers. 1024 blocks = (b,h,rowgroup).
// Fuses the l2-normalization of q,k (full-wave shuffle reduction over D=64).
__global__ __launch_bounds__(64) void scan_kernel(
    const float* __restrict__ q, const float* __restrict__ k,
    const float* __restrict__ v, const float* __restrict__ beta,
    float* __restrict__ o)
{
  const int bid = blockIdx.x;     // 0..1023
  const int b  = bid >> 8;
  const int h  = (bid >> 4) & 15;
  const int rg = bid & 15;        // row group: rows rg*4 .. rg*4+3
  const int lane = threadIdx.x;
  const int g  = lane & 15;       // column group: cols 4g..4g+3
  const int rr = lane >> 4;       // local row 0..3
  const int d  = rg * 4 + rr;     // my M row

  const size_t base = ((size_t)b * Tz) * Cz + (size_t)h * Dz;
  const float* qp = q + base + lane;
  const float* kp = k + base + lane;
  const float* vp = v + base + d;
  const float* bp = beta + ((size_t)b * Tz) * Hz + h;
  float* op = o + base + d;

  float m0 = 0.f, m1 = 0.f, m2 = 0.f, m3 = 0.f;  // M[d][4g+0..3]

  float rq = qp[0], rk = kp[0], rv = vp[0], rb = bp[0];

  for (int t = 0; t < Tz; ++t) {
    // register double-buffer: prefetch t+1 (waitcnt lands next iteration)
    float nq = 0.f, nk = 0.f, nv = 0.f, nb = 0.f;
    if (t + 1 < Tz) {
      int off = (t + 1) << 10;          // stride C=1024 floats
      nq = qp[off]; nk = kp[off]; nv = vp[off];
      nb = bp[(t + 1) << 4];
    }
    // l2norm over the 64 head dims (lane == dim)
    float sq = rq * rq, sk = rk * rk;
#pragma unroll
    for (int ofs = 32; ofs >= 1; ofs >>= 1) {
      sq += __shfl_xor(sq, ofs);
      sk += __shfl_xor(sk, ofs);
    }
    float qn = rq * rsqrtf(fmaxf(sq, 1e-24f));
    float kn = rk * rsqrtf(fmaxf(sk, 1e-24f));
    // broadcast my 4 columns' q,k values
    float q0 = __shfl(qn, 4 * g + 0), q1 = __shfl(qn, 4 * g + 1),
          q2 = __shfl(qn, 4 * g + 2), q3 = __shfl(qn, 4 * g + 3);
    float k0 = __shfl(kn, 4 * g + 0), k1 = __shfl(kn, 4 * g + 1),
          k2 = __shfl(kn, 4 * g + 2), k3 = __shfl(kn, 4 * g + 3);
    // o = M q, Mk = M k   (partial over my 4 cols, reduce over 16 lanes of row)
    float po = m0 * q0 + m1 * q1 + m2 * q2 + m3 * q3;
    float pk = m0 * k0 + m1 * k1 + m2 * k2 + m3 * k3;
#pragma unroll
    for (int ofs = 8; ofs >= 1; ofs >>= 1) {
      po += __shfl_xor(po, ofs);
      pk += __shfl_xor(pk, ofs);
    }
    float s = rb * (rv - pk);     // beta * (v[d] - (Mk)[d])
    m0 += s * k0; m1 += s * k1; m2 += s * k2; m3 += s * k3;
    if (g == 0) op[t << 10] = po; // 4 lanes write 16B contiguous
    rq = nq; rk = nk; rv = nv; rb = nb;
  }
}

// ---------------- gate*o -> bf16 ----------------
__global__ __launch_bounds__(256) void gate_mul_kernel(
    const float* __restrict__ gsig, const float* __restrict__ o,
    unsigned short* __restrict__ out, int n4)
{
  int i = blockIdx.x * blockDim.x + threadIdx.x;
  int stride = gridDim.x * blockDim.x;
  const float4* g4 = (const float4*)gsig;
  const float4* o4 = (const float4*)o;
  ushort4* out4 = (ushort4*)out;
  for (; i < n4; i += stride) {
    float4 gv = g4[i];
    float4 ov = o4[i];
    ushort4 u;
    u.x = f2bf(gv.x * ov.x);
    u.y = f2bf(gv.y * ov.y);
    u.z = f2bf(gv.z * ov.z);
    u.w = f2bf(gv.w * ov.w);
    out4[i] = u;
  }
}

extern "C" void kernel_launch(void* const* d_in, const int* in_sizes, int n_in,
                              void* d_out, int out_size, void* d_ws, size_t ws_size,
                              hipStream_t stream) {
  const float* x     = (const float*)d_in[0];
  const float* Wq    = (const float*)d_in[1];
  const float* Wk    = (const float*)d_in[2];
  const float* Wv    = (const float*)d_in[3];
  const float* Wbeta = (const float*)d_in[4];
  const float* bbeta = (const float*)d_in[5];
  const float* Wgate = (const float*)d_in[6];
  const float* Wo    = (const float*)d_in[7];
  float* out = (float*)d_out;

  char* ws = (char*)d_ws;
  size_t off = 0;
  auto alloc = [&](size_t bytes) -> char* {
    char* p = ws + off;
    off += (bytes + 255) & ~(size_t)255;
    return p;
  };
  unsigned short* xb  = (unsigned short*)alloc((size_t)NTOK * Cz * 2);  // bf16 x
  unsigned short* Wqb = (unsigned short*)alloc((size_t)Cz * Cz * 2);
  unsigned short* Wkb = (unsigned short*)alloc((size_t)Cz * Cz * 2);
  unsigned short* Wvb = (unsigned short*)alloc((size_t)Cz * Cz * 2);
  unsigned short* Wgb = (unsigned short*)alloc((size_t)Cz * Cz * 2);
  unsigned short* Wob = (unsigned short*)alloc((size_t)Cz * Cz * 2);
  float* qf    = (float*)alloc((size_t)NTOK * Cz * 4);
  float* kf    = (float*)alloc((size_t)NTOK * Cz * 4);
  float* vf    = (float*)alloc((size_t)NTOK * Cz * 4);
  float* gf    = (float*)alloc((size_t)NTOK * Cz * 4);  // sigmoid(gate) fp32
  float* of    = (float*)alloc((size_t)NTOK * Cz * 4);
  float* betaf = (float*)alloc((size_t)NTOK * Hz * 4);
  unsigned short* ab = xb;  // reuse xb: dead after the projection GEMMs
  // total ws use ~196 MB

  const int n4x = NTOK * Cz / 4;  // 2,097,152
  const int n4w = Cz * Cz / 4;    //   262,144

  cvt_bf16_kernel<<<dim3((n4x + 255) / 256), dim3(256), 0, stream>>>(x, xb, n4x);
  cvt_bf16_kernel<<<dim3((n4w + 255) / 256), dim3(256), 0, stream>>>(Wq, Wqb, n4w);
  cvt_bf16_kernel<<<dim3((n4w + 255) / 256), dim3(256), 0, stream>>>(Wk, Wkb, n4w);
  cvt_bf16_kernel<<<dim3((n4w + 255) / 256), dim3(256), 0, stream>>>(Wv, Wvb, n4w);
  cvt_bf16_kernel<<<dim3((n4w + 255) / 256), dim3(256), 0, stream>>>(Wgate, Wgb, n4w);
  cvt_bf16_kernel<<<dim3((n4w + 255) / 256), dim3(256), 0, stream>>>(Wo, Wob, n4w);

  // fused q,k,v,gate projections; z==3 (gate) gets sigmoid epilogue
  gemm_bt_kernel<<<dim3(Cz / 128, NTOK / 128, 4), dim3(256), 0, stream>>>(
      xb, Wqb, Wkb, Wvb, Wgb, qf, kf, vf, gf, NTOK, Cz, Cz, 3);

  beta_kernel<<<dim3(NTOK), dim3(256), 0, stream>>>(x, Wbeta, bbeta, betaf);

  scan_kernel<<<dim3(Bz * Hz * 16), dim3(64), 0, stream>>>(qf, kf, vf, betaf, of);

  gate_mul_kernel<<<dim3((n4x + 255) / 256), dim3(256), 0, stream>>>(gf, of, ab, n4x);

  // out = (gate*o) @ Wo^T
  gemm_bt_kernel<<<dim3(Cz / 128, NTOK / 128, 1), dim3(256), 0, stream>>>(
      ab, Wob, Wob, Wob, Wob, out, out, out, out, NTOK, Cz, Cz, -1);
}

// Round 2
// 1253.804 us; speedup vs baseline: 1.3467x; 1.3467x over previous
//
#include <hip/hip_runtime.h>
#include <cstdint>
#include <cstddef>

// Problem constants (B,T,C,H,D) = (4,2048,1024,16,64)
#define Bz 4
#define Tz 2048
#define Cz 1024
#define Hz 16
#define Dz 64
#define NTOK (Bz*Tz)   // 8192 tokens

typedef __attribute__((ext_vector_type(8))) short  short8;   // 8 x bf16 (4 VGPRs)
typedef __attribute__((ext_vector_type(4))) float  floatx4;  // MFMA accum

__device__ __forceinline__ unsigned short f2bf(float x) {
  // round-to-nearest-even fp32 -> bf16
  union { float f; uint32_t u; } a; a.f = x;
  uint32_t r = a.u + 0x7fffu + ((a.u >> 16) & 1u);
  return (unsigned short)(r >> 16);
}

__device__ __forceinline__ float sigmoidf_(float z) {
  return 1.0f / (1.0f + __expf(-z));
}

// async global->LDS 16B
__device__ __forceinline__ void gload_lds16(const void* gptr, void* lptr) {
  __builtin_amdgcn_global_load_lds(
      (const __attribute__((address_space(1))) void*)(uintptr_t)gptr,
      (__attribute__((address_space(3))) void*)(uint32_t)(uintptr_t)lptr,
      16, 0, 0);
}

// ---- DPP 16-lane row reduction (VALU-speed, no DS pipe) ----
template<int CTRL>
__device__ __forceinline__ float dpp_addf(float x) {
  int y = __builtin_amdgcn_update_dpp(0, __float_as_int(x), CTRL, 0xF, 0xF, true);
  return x + __int_as_float(y);
}
__device__ __forceinline__ float rowsum16(float x) {
  x = dpp_addf<0xB1>(x);   // quad_perm(1,0,3,2)  = xor 1
  x = dpp_addf<0x4E>(x);   // quad_perm(2,3,0,1)  = xor 2
  x = dpp_addf<0x124>(x);  // row_ror:4
  x = dpp_addf<0x128>(x);  // row_ror:8  -> full sum of 16 lanes in every lane
  return x;
}

// ---------------- fp32 -> bf16 convert ----------------
__global__ __launch_bounds__(256) void cvt_bf16_kernel(const float* __restrict__ in,
                                                       unsigned short* __restrict__ out,
                                                       int n4) {
  int i = blockIdx.x * blockDim.x + threadIdx.x;
  int stride = gridDim.x * blockDim.x;
  const float4* in4 = (const float4*)in;
  ushort4* out4 = (ushort4*)out;
  for (; i < n4; i += stride) {
    float4 f = in4[i];
    ushort4 u;
    u.x = f2bf(f.x); u.y = f2bf(f.y); u.z = f2bf(f.z); u.w = f2bf(f.w);
    out4[i] = u;
  }
}

// ---------------- bf16 MFMA GEMM: C[m,n] = sum_k A[m,k]*B[n,k] ----------------
__global__ __launch_bounds__(256) void gemm_bt_kernel(
    const unsigned short* __restrict__ A,
    const unsigned short* __restrict__ W0, const unsigned short* __restrict__ W1,
    const unsigned short* __restrict__ W2, const unsigned short* __restrict__ W3,
    float* __restrict__ O0, float* __restrict__ O1,
    float* __restrict__ O2, float* __restrict__ O3,
    int M, int N, int K, int nz_sigmoid)
{
  const int z = blockIdx.z;
  const unsigned short* Bw = (z == 0) ? W0 : (z == 1) ? W1 : (z == 2) ? W2 : W3;
  float* Cw = (z == 0) ? O0 : (z == 1) ? O1 : (z == 2) ? O2 : O3;
  const bool act = (z == nz_sigmoid);

  __shared__ unsigned short As[128 * 32];
  __shared__ unsigned short Bs[128 * 32];

  const int tid  = threadIdx.x;
  const int wid  = tid >> 6;
  const int lane = tid & 63;
  const int wm = wid & 1, wn = wid >> 1;
  const int m0 = blockIdx.y * 128;
  const int n0 = blockIdx.x * 128;

  const int srow = tid >> 2;
  const int scol = (tid & 3) * 8;

  floatx4 acc[4][4];
#pragma unroll
  for (int i = 0; i < 4; ++i)
#pragma unroll
    for (int j = 0; j < 4; ++j)
      acc[i][j] = floatx4{0.f, 0.f, 0.f, 0.f};

  const int ml = lane & 15;
  const int kq = lane >> 4;

  const unsigned short* Arow0 = A  + (size_t)(m0 + srow) * K + scol;
  const unsigned short* Arow1 = A  + (size_t)(m0 + 64 + srow) * K + scol;
  const unsigned short* Brow0 = Bw + (size_t)(n0 + srow) * K + scol;
  const unsigned short* Brow1 = Bw + (size_t)(n0 + 64 + srow) * K + scol;

  for (int kt = 0; kt < K; kt += 32) {
    gload_lds16(Arow0 + kt, &As[wid * 512]);
    gload_lds16(Arow1 + kt, &As[2048 + wid * 512]);
    gload_lds16(Brow0 + kt, &Bs[wid * 512]);
    gload_lds16(Brow1 + kt, &Bs[2048 + wid * 512]);
    __syncthreads();

    short8 af[4], bfv[4];
#pragma unroll
    for (int i = 0; i < 4; ++i) {
      af[i]  = *(const short8*)&As[(wm * 64 + i * 16 + ml) * 32 + kq * 8];
      bfv[i] = *(const short8*)&Bs[(wn * 64 + i * 16 + ml) * 32 + kq * 8];
    }
#pragma unroll
    for (int i = 0; i < 4; ++i)
#pragma unroll
      for (int j = 0; j < 4; ++j)
        acc[i][j] = __builtin_amdgcn_mfma_f32_16x16x32_bf16(af[i], bfv[j], acc[i][j], 0, 0, 0);
    __syncthreads();
  }

  const int row_base = m0 + wm * 64;
  const int col_base = n0 + wn * 64;
#pragma unroll
  for (int i = 0; i < 4; ++i) {
#pragma unroll
    for (int j = 0; j < 4; ++j) {
      int col = col_base + j * 16 + ml;
#pragma unroll
      for (int r = 0; r < 4; ++r) {
        int row = row_base + i * 16 + kq * 4 + r;
        float val = acc[i][j][r];
        if (act) val = sigmoidf_(val);
        Cw[(size_t)row * N + col] = val;
      }
    }
  }
}

// ---------------- beta projection (fp32, exact) ----------------
__global__ __launch_bounds__(256) void beta_kernel(
    const float* __restrict__ x, const float* __restrict__ Wb,
    const float* __restrict__ bb, float* __restrict__ beta_out)
{
  const int n = blockIdx.x;
  const int wid = threadIdx.x >> 6;
  const int lane = threadIdx.x & 63;
  const float* xr = x + (size_t)n * Cz;
  for (int h = wid; h < Hz; h += 4) {
    const float* wr = Wb + (size_t)h * Cz;
    float s = 0.f;
#pragma unroll 4
    for (int i = lane; i < Cz; i += 64) s = fmaf(xr[i], wr[i], s);
#pragma unroll
    for (int ofs = 32; ofs >= 1; ofs >>= 1) s += __shfl_xor(s, ofs);
    if (lane == 0) beta_out[(size_t)n * Hz + h] = sigmoidf_(s + bb[h]);
  }
}

// ---------------- delta-rule scan v2 ----------------
// Per chain (b,h): 16 single-wave blocks, each owns 4 rows of the 64x64 state M.
// Lane (rr,g): rr=lane>>4 row within group, g=lane&15 column group (cols 4g..4g+3).
// Each lane LOADS its q/k column quad directly as float4 (no broadcast shuffle);
// 16-lane reductions via DPP (VALU, no DS pipe); l2norm computed off the m-cycle.
// XCD swizzle: chain = bid&63 so all 16 row-groups of a chain share an XCD's L2.
__global__ __launch_bounds__(64) void scan_kernel(
    const float* __restrict__ q, const float* __restrict__ k,
    const float* __restrict__ v, const float* __restrict__ beta,
    float* __restrict__ o)
{
  const int bid = blockIdx.x;     // 0..1023
  const int chain = bid & 63;     // (b,h); bid%8 == chain%8 -> same XCD per chain
  const int rg = bid >> 6;        // row group: rows rg*4 .. rg*4+3
  const int b = chain >> 4;
  const int h = chain & 15;
  const int lane = threadIdx.x;
  const int g  = lane & 15;
  const int rr = lane >> 4;
  const int d  = rg * 4 + rr;

  const size_t cbase = ((size_t)b * Tz) * Cz + (size_t)h * Dz;
  const float4* q4 = (const float4*)(q + cbase);
  const float4* k4 = (const float4*)(k + cbase);
  const float* vp = v + cbase + d;
  const float* bp = beta + ((size_t)b * Tz) * Hz + h;
  float* op = o + cbase + d;
  const int C4 = Cz / 4;  // 256 float4 per token-row stride

  float m0 = 0.f, m1 = 0.f, m2 = 0.f, m3 = 0.f;

  float4 cq[4], ck[4]; float cv[4], cb[4];
#pragma unroll
  for (int j = 0; j < 4; ++j) {
    cq[j] = q4[(size_t)j * C4 + g];
    ck[j] = k4[(size_t)j * C4 + g];
    cv[j] = vp[(size_t)j * Cz];
    cb[j] = bp[(size_t)j * Hz];
  }

  for (int t0 = 0; t0 < Tz; t0 += 4) {
    // prefetch next group of 4 steps (distance ~4-8 steps hides L2 latency)
    float4 nq[4], nk[4]; float nv[4], nb[4];
    if (t0 + 4 < Tz) {
#pragma unroll
      for (int j = 0; j < 4; ++j) {
        size_t tt = (size_t)(t0 + 4 + j);
        nq[j] = q4[tt * C4 + g];
        nk[j] = k4[tt * C4 + g];
        nv[j] = vp[tt * Cz];
        nb[j] = bp[tt * Hz];
      }
    } else {
#pragma unroll
      for (int j = 0; j < 4; ++j) {
        nq[j] = float4{0,0,0,0}; nk[j] = float4{0,0,0,0}; nv[j] = 0.f; nb[j] = 0.f;
      }
    }

    // pre-pass: l2-normalize current 4 steps (independent of M -> off the cycle)
#pragma unroll
    for (int j = 0; j < 4; ++j) {
      float4 qv = cq[j], kv = ck[j];
      float sq = qv.x*qv.x + qv.y*qv.y + qv.z*qv.z + qv.w*qv.w;
      float sk = kv.x*kv.x + kv.y*kv.y + kv.z*kv.z + kv.w*kv.w;
      sq = rowsum16(sq);                 // sum over all 64 head dims
      sk = rowsum16(sk);
      float qs = 1.0f / fmaxf(sqrtf(sq), 1e-12f);
      float ks = 1.0f / fmaxf(sqrtf(sk), 1e-12f);
      cq[j].x = qv.x*qs; cq[j].y = qv.y*qs; cq[j].z = qv.z*qs; cq[j].w = qv.w*qs;
      ck[j].x = kv.x*ks; ck[j].y = kv.y*ks; ck[j].z = kv.z*ks; ck[j].w = kv.w*ks;
    }

    // sequential m-cycle: 4 FMA + 4 DPP-adds + 2 ALU + 1 FMA per step
#pragma unroll
    for (int j = 0; j < 4; ++j) {
      float4 qv = cq[j], kv = ck[j];
      float pk = m0*kv.x + m1*kv.y + m2*kv.z + m3*kv.w;
      float po = m0*qv.x + m1*qv.y + m2*qv.z + m3*qv.w;
      pk = rowsum16(pk);
      po = rowsum16(po);
      float s = cb[j] * (cv[j] - pk);
      m0 = fmaf(s, kv.x, m0);
      m1 = fmaf(s, kv.y, m1);
      m2 = fmaf(s, kv.z, m2);
      m3 = fmaf(s, kv.w, m3);
      if (g == 0) op[(size_t)(t0 + j) * Cz] = po;  // lanes 0,16,32,48 -> 16B contig
    }

#pragma unroll
    for (int j = 0; j < 4; ++j) { cq[j] = nq[j]; ck[j] = nk[j]; cv[j] = nv[j]; cb[j] = nb[j]; }
  }
}

// ---------------- gate*o -> bf16 ----------------
__global__ __launch_bounds__(256) void gate_mul_kernel(
    const float* __restrict__ gsig, const float* __restrict__ o,
    unsigned short* __restrict__ out, int n4)
{
  int i = blockIdx.x * blockDim.x + threadIdx.x;
  int stride = gridDim.x * blockDim.x;
  const float4* g4 = (const float4*)gsig;
  const float4* o4 = (const float4*)o;
  ushort4* out4 = (ushort4*)out;
  for (; i < n4; i += stride) {
    float4 gv = g4[i];
    float4 ov = o4[i];
    ushort4 u;
    u.x = f2bf(gv.x * ov.x);
    u.y = f2bf(gv.y * ov.y);
    u.z = f2bf(gv.z * ov.z);
    u.w = f2bf(gv.w * ov.w);
    out4[i] = u;
  }
}

extern "C" void kernel_launch(void* const* d_in, const int* in_sizes, int n_in,
                              void* d_out, int out_size, void* d_ws, size_t ws_size,
                              hipStream_t stream) {
  const float* x     = (const float*)d_in[0];
  const float* Wq    = (const float*)d_in[1];
  const float* Wk    = (const float*)d_in[2];
  const float* Wv    = (const float*)d_in[3];
  const float* Wbeta = (const float*)d_in[4];
  const float* bbeta = (const float*)d_in[5];
  const float* Wgate = (const float*)d_in[6];
  const float* Wo    = (const float*)d_in[7];
  float* out = (float*)d_out;

  char* ws = (char*)d_ws;
  size_t off = 0;
  auto alloc = [&](size_t bytes) -> char* {
    char* p = ws + off;
    off += (bytes + 255) & ~(size_t)255;
    return p;
  };
  unsigned short* xb  = (unsigned short*)alloc((size_t)NTOK * Cz * 2);
  unsigned short* Wqb = (unsigned short*)alloc((size_t)Cz * Cz * 2);
  unsigned short* Wkb = (unsigned short*)alloc((size_t)Cz * Cz * 2);
  unsigned short* Wvb = (unsigned short*)alloc((size_t)Cz * Cz * 2);
  unsigned short* Wgb = (unsigned short*)alloc((size_t)Cz * Cz * 2);
  unsigned short* Wob = (unsigned short*)alloc((size_t)Cz * Cz * 2);
  float* qf    = (float*)alloc((size_t)NTOK * Cz * 4);
  float* kf    = (float*)alloc((size_t)NTOK * Cz * 4);
  float* vf    = (float*)alloc((size_t)NTOK * Cz * 4);
  float* gf    = (float*)alloc((size_t)NTOK * Cz * 4);
  float* of    = (float*)alloc((size_t)NTOK * Cz * 4);
  float* betaf = (float*)alloc((size_t)NTOK * Hz * 4);
  unsigned short* ab = xb;  // reuse xb after projection GEMMs

  const int n4x = NTOK * Cz / 4;
  const int n4w = Cz * Cz / 4;

  cvt_bf16_kernel<<<dim3((n4x + 255) / 256), dim3(256), 0, stream>>>(x, xb, n4x);
  cvt_bf16_kernel<<<dim3((n4w + 255) / 256), dim3(256), 0, stream>>>(Wq, Wqb, n4w);
  cvt_bf16_kernel<<<dim3((n4w + 255) / 256), dim3(256), 0, stream>>>(Wk, Wkb, n4w);
  cvt_bf16_kernel<<<dim3((n4w + 255) / 256), dim3(256), 0, stream>>>(Wv, Wvb, n4w);
  cvt_bf16_kernel<<<dim3((n4w + 255) / 256), dim3(256), 0, stream>>>(Wgate, Wgb, n4w);
  cvt_bf16_kernel<<<dim3((n4w + 255) / 256), dim3(256), 0, stream>>>(Wo, Wob, n4w);

  gemm_bt_kernel<<<dim3(Cz / 128, NTOK / 128, 4), dim3(256), 0, stream>>>(
      xb, Wqb, Wkb, Wvb, Wgb, qf, kf, vf, gf, NTOK, Cz, Cz, 3);

  beta_kernel<<<dim3(NTOK), dim3(256), 0, stream>>>(x, Wbeta, bbeta, betaf);

  scan_kernel<<<dim3(Bz * Hz * 16), dim3(64), 0, stream>>>(qf, kf, vf, betaf, of);

  gate_mul_kernel<<<dim3((n4x + 255) / 256), dim3(256), 0, stream>>>(gf, of, ab, n4x);

  gemm_bt_kernel<<<dim3(Cz / 128, NTOK / 128, 1), dim3(256), 0, stream>>>(
      ab, Wob, Wob, Wob, Wob, out, out, out, out, NTOK, Cz, Cz, -1);
}

// Round 3
// 628.358 us; speedup vs baseline: 2.6871x; 1.9954x over previous
//
#include <hip/hip_runtime.h>
#include <cstdint>
#include <cstddef>

// Problem constants (B,T,C,H,D) = (4,2048,1024,16,64)
#define Bz 4
#define Tz 2048
#define Cz 1024
#define Hz 16
#define Dz 64
#define NTOK (Bz*Tz)   // 8192 tokens

typedef __attribute__((ext_vector_type(8))) short  short8;   // 8 x bf16 (4 VGPRs)
typedef __attribute__((ext_vector_type(4))) float  floatx4;  // MFMA accum

__device__ __forceinline__ unsigned short f2bf(float x) {
  union { float f; uint32_t u; } a; a.f = x;
  uint32_t r = a.u + 0x7fffu + ((a.u >> 16) & 1u);
  return (unsigned short)(r >> 16);
}

__device__ __forceinline__ float sigmoidf_(float z) {
  return 1.0f / (1.0f + __expf(-z));
}

// async global->LDS 16B
__device__ __forceinline__ void gload_lds16(const void* gptr, void* lptr) {
  __builtin_amdgcn_global_load_lds(
      (const __attribute__((address_space(1))) void*)(uintptr_t)gptr,
      (__attribute__((address_space(3))) void*)(uint32_t)(uintptr_t)lptr,
      16, 0, 0);
}

// ---- DPP 16-lane row reduction (VALU-speed, no DS pipe) ----
template<int CTRL>
__device__ __forceinline__ float dpp_addf(float x) {
  int y = __builtin_amdgcn_update_dpp(0, __float_as_int(x), CTRL, 0xF, 0xF, true);
  return x + __int_as_float(y);
}
__device__ __forceinline__ float rowsum16(float x) {
  x = dpp_addf<0xB1>(x);   // quad_perm(1,0,3,2)  = xor 1
  x = dpp_addf<0x4E>(x);   // quad_perm(2,3,0,1)  = xor 2
  x = dpp_addf<0x124>(x);  // row_ror:4
  x = dpp_addf<0x128>(x);  // row_ror:8  -> full 16-lane sum in every lane
  return x;
}

// ---------------- fp32 -> bf16 convert ----------------
__global__ __launch_bounds__(256) void cvt_bf16_kernel(const float* __restrict__ in,
                                                       unsigned short* __restrict__ out,
                                                       int n4) {
  int i = blockIdx.x * blockDim.x + threadIdx.x;
  int stride = gridDim.x * blockDim.x;
  const float4* in4 = (const float4*)in;
  ushort4* out4 = (ushort4*)out;
  for (; i < n4; i += stride) {
    float4 f = in4[i];
    ushort4 u;
    u.x = f2bf(f.x); u.y = f2bf(f.y); u.z = f2bf(f.z); u.w = f2bf(f.w);
    out4[i] = u;
  }
}

// ---------------- bf16 MFMA GEMM: C[m,n] = sum_k A[m,k]*B[n,k] ----------------
// norm_mask bit z: apply per-64-col (per-head) l2 normalization in the epilogue.
// Wave quadrant = 64 cols = exactly one head (n0 % 128 == 0, D = 64).
__global__ __launch_bounds__(256) void gemm_bt_kernel(
    const unsigned short* __restrict__ A,
    const unsigned short* __restrict__ W0, const unsigned short* __restrict__ W1,
    const unsigned short* __restrict__ W2, const unsigned short* __restrict__ W3,
    float* __restrict__ O0, float* __restrict__ O1,
    float* __restrict__ O2, float* __restrict__ O3,
    int M, int N, int K, int nz_sigmoid, int norm_mask)
{
  const int z = blockIdx.z;
  const unsigned short* Bw = (z == 0) ? W0 : (z == 1) ? W1 : (z == 2) ? W2 : W3;
  float* Cw = (z == 0) ? O0 : (z == 1) ? O1 : (z == 2) ? O2 : O3;
  const bool act = (z == nz_sigmoid);
  const bool donorm = (norm_mask >> z) & 1;

  __shared__ unsigned short As[128 * 32];
  __shared__ unsigned short Bs[128 * 32];

  const int tid  = threadIdx.x;
  const int wid  = tid >> 6;
  const int lane = tid & 63;
  const int wm = wid & 1, wn = wid >> 1;
  const int m0 = blockIdx.y * 128;
  const int n0 = blockIdx.x * 128;

  const int srow = tid >> 2;
  const int scol = (tid & 3) * 8;

  floatx4 acc[4][4];
#pragma unroll
  for (int i = 0; i < 4; ++i)
#pragma unroll
    for (int j = 0; j < 4; ++j)
      acc[i][j] = floatx4{0.f, 0.f, 0.f, 0.f};

  const int ml = lane & 15;
  const int kq = lane >> 4;

  const unsigned short* Arow0 = A  + (size_t)(m0 + srow) * K + scol;
  const unsigned short* Arow1 = A  + (size_t)(m0 + 64 + srow) * K + scol;
  const unsigned short* Brow0 = Bw + (size_t)(n0 + srow) * K + scol;
  const unsigned short* Brow1 = Bw + (size_t)(n0 + 64 + srow) * K + scol;

  for (int kt = 0; kt < K; kt += 32) {
    gload_lds16(Arow0 + kt, &As[wid * 512]);
    gload_lds16(Arow1 + kt, &As[2048 + wid * 512]);
    gload_lds16(Brow0 + kt, &Bs[wid * 512]);
    gload_lds16(Brow1 + kt, &Bs[2048 + wid * 512]);
    __syncthreads();

    short8 af[4], bfv[4];
#pragma unroll
    for (int i = 0; i < 4; ++i) {
      af[i]  = *(const short8*)&As[(wm * 64 + i * 16 + ml) * 32 + kq * 8];
      bfv[i] = *(const short8*)&Bs[(wn * 64 + i * 16 + ml) * 32 + kq * 8];
    }
#pragma unroll
    for (int i = 0; i < 4; ++i)
#pragma unroll
      for (int j = 0; j < 4; ++j)
        acc[i][j] = __builtin_amdgcn_mfma_f32_16x16x32_bf16(af[i], bfv[j], acc[i][j], 0, 0, 0);
    __syncthreads();
  }

  // per-row l2norm scale: one output row's 64 cols live in the 16 lanes sharing kq
  float scale[4][4];
  if (donorm) {
#pragma unroll
    for (int i = 0; i < 4; ++i) {
#pragma unroll
      for (int r = 0; r < 4; ++r) {
        float ss = 0.f;
#pragma unroll
        for (int j = 0; j < 4; ++j) ss = fmaf(acc[i][j][r], acc[i][j][r], ss);
        ss = rowsum16(ss);
        scale[i][r] = 1.0f / fmaxf(sqrtf(ss), 1e-12f);
      }
    }
  }

  const int row_base = m0 + wm * 64;
  const int col_base = n0 + wn * 64;
#pragma unroll
  for (int i = 0; i < 4; ++i) {
#pragma unroll
    for (int j = 0; j < 4; ++j) {
      int col = col_base + j * 16 + ml;
#pragma unroll
      for (int r = 0; r < 4; ++r) {
        int row = row_base + i * 16 + kq * 4 + r;
        float val = acc[i][j][r];
        if (donorm) val *= scale[i][r];
        if (act) val = sigmoidf_(val);
        Cw[(size_t)row * N + col] = val;
      }
    }
  }
}

// ---------------- beta projection (fp32, exact) ----------------
__global__ __launch_bounds__(256) void beta_kernel(
    const float* __restrict__ x, const float* __restrict__ Wb,
    const float* __restrict__ bb, float* __restrict__ beta_out)
{
  const int n = blockIdx.x;
  const int wid = threadIdx.x >> 6;
  const int lane = threadIdx.x & 63;
  const float* xr = x + (size_t)n * Cz;
  for (int h = wid; h < Hz; h += 4) {
    const float* wr = Wb + (size_t)h * Cz;
    float s = 0.f;
#pragma unroll 4
    for (int i = lane; i < Cz; i += 64) s = fmaf(xr[i], wr[i], s);
#pragma unroll
    for (int ofs = 32; ofs >= 1; ofs >>= 1) s += __shfl_xor(s, ofs);
    if (lane == 0) beta_out[(size_t)n * Hz + h] = sigmoidf_(s + bb[h]);
  }
}

// ---------------- delta-rule scan v3 ----------------
// Inputs q,k are PRE-NORMALIZED (GEMM epilogue). Per chain (b,h): 16 single-wave
// blocks, each owns 4 rows of the 64x64 state M in registers. Lane (rr,g):
// rr=lane>>4 row, g=lane&15 -> cols 4g..4g+3. 16-lane reductions via DPP.
// 16-step (4-group) rotating register pipeline hides HBM/L3 load latency.
// po reduction deferred off the m-recurrence critical path.
__global__ __launch_bounds__(64, 1) void scan_kernel(
    const float* __restrict__ q, const float* __restrict__ k,
    const float* __restrict__ v, const float* __restrict__ beta,
    float* __restrict__ o)
{
  const int bid = blockIdx.x;     // 0..1023
  const int chain = bid & 63;     // (b,h); bid%8 -> XCD: all row-groups share L2
  const int rg = bid >> 6;        // row group: rows rg*4 .. rg*4+3
  const int b = chain >> 4;
  const int h = chain & 15;
  const int lane = threadIdx.x;
  const int g  = lane & 15;
  const int rr = lane >> 4;
  const int d  = rg * 4 + rr;

  const size_t cbase = ((size_t)b * Tz) * Cz + (size_t)h * Dz;
  const float4* q4 = (const float4*)(q + cbase);
  const float4* k4 = (const float4*)(k + cbase);
  const float* vp = v + cbase + d;
  const float* bp = beta + ((size_t)b * Tz) * Hz + h;
  float* op = o + cbase + d;
  const int C4 = Cz / 4;

  float4 bq[4][4], bk[4][4];
  float  bv[4][4], bbt[4][4];

  auto ldgrp = [&](int p, int t) {
#pragma unroll
    for (int j = 0; j < 4; ++j) {
      int tt = t + j; tt = tt < Tz ? tt : Tz - 1;   // clamped (tail overruns harmless)
      bq[p][j]  = q4[(size_t)tt * C4 + g];
      bk[p][j]  = k4[(size_t)tt * C4 + g];
      bv[p][j]  = vp[(size_t)tt * Cz];
      bbt[p][j] = bp[(size_t)tt * Hz];
    }
  };

#pragma unroll
  for (int p = 0; p < 4; ++p) ldgrp(p, p * 4);   // prologue: 16 steps in flight

  float m0 = 0.f, m1 = 0.f, m2 = 0.f, m3 = 0.f;

  for (int t0 = 0; t0 < Tz; t0 += 16) {
#pragma unroll
    for (int p = 0; p < 4; ++p) {
      const int tb = t0 + p * 4;
      float po_s[4];
#pragma unroll
      for (int j = 0; j < 4; ++j) {
        float4 kv = bk[p][j];
        float4 qv = bq[p][j];
        // critical path: pk tree -> rowsum16 -> s -> m update
        float pk = fmaf(m0, kv.x, m1 * kv.y) + fmaf(m2, kv.z, m3 * kv.w);
        pk = rowsum16(pk);
        // po partial from PRE-update M (reduction deferred off-path)
        po_s[j] = fmaf(m0, qv.x, m1 * qv.y) + fmaf(m2, qv.z, m3 * qv.w);
        float s = bbt[p][j] * (bv[p][j] - pk);
        m0 = fmaf(s, kv.x, m0);
        m1 = fmaf(s, kv.y, m1);
        m2 = fmaf(s, kv.z, m2);
        m3 = fmaf(s, kv.w, m3);
      }
      // refill this slot for t+16 (stays 3 groups ahead of consumption)
      ldgrp(p, tb + 16);
      // deferred po reductions + store (independent DPP chains, interleave)
#pragma unroll
      for (int j = 0; j < 4; ++j) {
        float pr = rowsum16(po_s[j]);
        if (g == 0) op[(size_t)(tb + j) * Cz] = pr;  // lanes 0,16,32,48: 16B contig
      }
    }
  }
}

// ---------------- gate*o -> bf16 ----------------
__global__ __launch_bounds__(256) void gate_mul_kernel(
    const float* __restrict__ gsig, const float* __restrict__ o,
    unsigned short* __restrict__ out, int n4)
{
  int i = blockIdx.x * blockDim.x + threadIdx.x;
  int stride = gridDim.x * blockDim.x;
  const float4* g4 = (const float4*)gsig;
  const float4* o4 = (const float4*)o;
  ushort4* out4 = (ushort4*)out;
  for (; i < n4; i += stride) {
    float4 gv = g4[i];
    float4 ov = o4[i];
    ushort4 u;
    u.x = f2bf(gv.x * ov.x);
    u.y = f2bf(gv.y * ov.y);
    u.z = f2bf(gv.z * ov.z);
    u.w = f2bf(gv.w * ov.w);
    out4[i] = u;
  }
}

extern "C" void kernel_launch(void* const* d_in, const int* in_sizes, int n_in,
                              void* d_out, int out_size, void* d_ws, size_t ws_size,
                              hipStream_t stream) {
  const float* x     = (const float*)d_in[0];
  const float* Wq    = (const float*)d_in[1];
  const float* Wk    = (const float*)d_in[2];
  const float* Wv    = (const float*)d_in[3];
  const float* Wbeta = (const float*)d_in[4];
  const float* bbeta = (const float*)d_in[5];
  const float* Wgate = (const float*)d_in[6];
  const float* Wo    = (const float*)d_in[7];
  float* out = (float*)d_out;

  char* ws = (char*)d_ws;
  size_t off = 0;
  auto alloc = [&](size_t bytes) -> char* {
    char* p = ws + off;
    off += (bytes + 255) & ~(size_t)255;
    return p;
  };
  unsigned short* xb  = (unsigned short*)alloc((size_t)NTOK * Cz * 2);
  unsigned short* Wqb = (unsigned short*)alloc((size_t)Cz * Cz * 2);
  unsigned short* Wkb = (unsigned short*)alloc((size_t)Cz * Cz * 2);
  unsigned short* Wvb = (unsigned short*)alloc((size_t)Cz * Cz * 2);
  unsigned short* Wgb = (unsigned short*)alloc((size_t)Cz * Cz * 2);
  unsigned short* Wob = (unsigned short*)alloc((size_t)Cz * Cz * 2);
  float* qf    = (float*)alloc((size_t)NTOK * Cz * 4);
  float* kf    = (float*)alloc((size_t)NTOK * Cz * 4);
  float* vf    = (float*)alloc((size_t)NTOK * Cz * 4);
  float* gf    = (float*)alloc((size_t)NTOK * Cz * 4);
  float* of    = (float*)alloc((size_t)NTOK * Cz * 4);
  float* betaf = (float*)alloc((size_t)NTOK * Hz * 4);
  unsigned short* ab = xb;  // reuse xb after projection GEMMs

  const int n4x = NTOK * Cz / 4;
  const int n4w = Cz * Cz / 4;

  cvt_bf16_kernel<<<dim3((n4x + 255) / 256), dim3(256), 0, stream>>>(x, xb, n4x);
  cvt_bf16_kernel<<<dim3((n4w + 255) / 256), dim3(256), 0, stream>>>(Wq, Wqb, n4w);
  cvt_bf16_kernel<<<dim3((n4w + 255) / 256), dim3(256), 0, stream>>>(Wk, Wkb, n4w);
  cvt_bf16_kernel<<<dim3((n4w + 255) / 256), dim3(256), 0, stream>>>(Wv, Wvb, n4w);
  cvt_bf16_kernel<<<dim3((n4w + 255) / 256), dim3(256), 0, stream>>>(Wgate, Wgb, n4w);
  cvt_bf16_kernel<<<dim3((n4w + 255) / 256), dim3(256), 0, stream>>>(Wo, Wob, n4w);

  // fused q,k,v,gate projections; q,k get l2norm epilogue (norm_mask=3), gate sigmoid
  gemm_bt_kernel<<<dim3(Cz / 128, NTOK / 128, 4), dim3(256), 0, stream>>>(
      xb, Wqb, Wkb, Wvb, Wgb, qf, kf, vf, gf, NTOK, Cz, Cz, 3, 3);

  beta_kernel<<<dim3(NTOK), dim3(256), 0, stream>>>(x, Wbeta, bbeta, betaf);

  scan_kernel<<<dim3(Bz * Hz * 16), dim3(64), 0, stream>>>(qf, kf, vf, betaf, of);

  gate_mul_kernel<<<dim3((n4x + 255) / 256), dim3(256), 0, stream>>>(gf, of, ab, n4x);

  gemm_bt_kernel<<<dim3(Cz / 128, NTOK / 128, 1), dim3(256), 0, stream>>>(
      ab, Wob, Wob, Wob, Wob, out, out, out, out, NTOK, Cz, Cz, -1, 0);
}

// Round 4
// 570.283 us; speedup vs baseline: 2.9608x; 1.1018x over previous
//
#include <hip/hip_runtime.h>
#include <cstdint>
#include <cstddef>

// Problem constants (B,T,C,H,D) = (4,2048,1024,16,64)
#define Bz 4
#define Tz 2048
#define Cz 1024
#define Hz 16
#define Dz 64
#define NTOK (Bz*Tz)   // 8192 tokens

typedef __attribute__((ext_vector_type(8))) short  short8;   // 8 x bf16 (4 VGPRs)
typedef __attribute__((ext_vector_type(4))) float  floatx4;  // MFMA accum

__device__ __forceinline__ unsigned short f2bf(float x) {
  union { float f; uint32_t u; } a; a.f = x;
  uint32_t r = a.u + 0x7fffu + ((a.u >> 16) & 1u);
  return (unsigned short)(r >> 16);
}

__device__ __forceinline__ float sigmoidf_(float z) {
  return 1.0f / (1.0f + __expf(-z));
}

// async global->LDS DMA (dest = wave-uniform LDS base + lane*size)
__device__ __forceinline__ void gload_lds16(const void* gptr, void* lptr) {
  __builtin_amdgcn_global_load_lds(
      (const __attribute__((address_space(1))) void*)(uintptr_t)gptr,
      (__attribute__((address_space(3))) void*)(uint32_t)(uintptr_t)lptr,
      16, 0, 0);
}
__device__ __forceinline__ void gload_lds4(const void* gptr, void* lptr) {
  __builtin_amdgcn_global_load_lds(
      (const __attribute__((address_space(1))) void*)(uintptr_t)gptr,
      (__attribute__((address_space(3))) void*)(uint32_t)(uintptr_t)lptr,
      4, 0, 0);
}

// ---- DPP 16-lane row reduction (VALU-speed, no DS pipe) ----
template<int CTRL>
__device__ __forceinline__ float dpp_addf(float x) {
  int y = __builtin_amdgcn_update_dpp(0, __float_as_int(x), CTRL, 0xF, 0xF, true);
  return x + __int_as_float(y);
}
__device__ __forceinline__ float rowsum16(float x) {
  x = dpp_addf<0xB1>(x);   // quad_perm xor1
  x = dpp_addf<0x4E>(x);   // quad_perm xor2
  x = dpp_addf<0x124>(x);  // row_ror:4
  x = dpp_addf<0x128>(x);  // row_ror:8  -> full 16-lane-row sum in every lane
  return x;
}

// ---------------- fp32 -> bf16 convert ----------------
__global__ __launch_bounds__(256) void cvt_bf16_kernel(const float* __restrict__ in,
                                                       unsigned short* __restrict__ out,
                                                       int n4) {
  int i = blockIdx.x * blockDim.x + threadIdx.x;
  int stride = gridDim.x * blockDim.x;
  const float4* in4 = (const float4*)in;
  ushort4* out4 = (ushort4*)out;
  for (; i < n4; i += stride) {
    float4 f = in4[i];
    ushort4 u;
    u.x = f2bf(f.x); u.y = f2bf(f.y); u.z = f2bf(f.z); u.w = f2bf(f.w);
    out4[i] = u;
  }
}

// ---------------- bf16 MFMA GEMM: C[m,n] = sum_k A[m,k]*B[n,k] ----------------
// norm_mask bit z: per-64-col (per-head) l2 normalization in the epilogue.
__global__ __launch_bounds__(256) void gemm_bt_kernel(
    const unsigned short* __restrict__ A,
    const unsigned short* __restrict__ W0, const unsigned short* __restrict__ W1,
    const unsigned short* __restrict__ W2, const unsigned short* __restrict__ W3,
    float* __restrict__ O0, float* __restrict__ O1,
    float* __restrict__ O2, float* __restrict__ O3,
    int M, int N, int K, int nz_sigmoid, int norm_mask)
{
  const int z = blockIdx.z;
  const unsigned short* Bw = (z == 0) ? W0 : (z == 1) ? W1 : (z == 2) ? W2 : W3;
  float* Cw = (z == 0) ? O0 : (z == 1) ? O1 : (z == 2) ? O2 : O3;
  const bool act = (z == nz_sigmoid);
  const bool donorm = (norm_mask >> z) & 1;

  __shared__ unsigned short As[128 * 32];
  __shared__ unsigned short Bs[128 * 32];

  const int tid  = threadIdx.x;
  const int wid  = tid >> 6;
  const int lane = tid & 63;
  const int wm = wid & 1, wn = wid >> 1;
  const int m0 = blockIdx.y * 128;
  const int n0 = blockIdx.x * 128;

  const int srow = tid >> 2;
  const int scol = (tid & 3) * 8;

  floatx4 acc[4][4];
#pragma unroll
  for (int i = 0; i < 4; ++i)
#pragma unroll
    for (int j = 0; j < 4; ++j)
      acc[i][j] = floatx4{0.f, 0.f, 0.f, 0.f};

  const int ml = lane & 15;
  const int kq = lane >> 4;

  const unsigned short* Arow0 = A  + (size_t)(m0 + srow) * K + scol;
  const unsigned short* Arow1 = A  + (size_t)(m0 + 64 + srow) * K + scol;
  const unsigned short* Brow0 = Bw + (size_t)(n0 + srow) * K + scol;
  const unsigned short* Brow1 = Bw + (size_t)(n0 + 64 + srow) * K + scol;

  for (int kt = 0; kt < K; kt += 32) {
    gload_lds16(Arow0 + kt, &As[wid * 512]);
    gload_lds16(Arow1 + kt, &As[2048 + wid * 512]);
    gload_lds16(Brow0 + kt, &Bs[wid * 512]);
    gload_lds16(Brow1 + kt, &Bs[2048 + wid * 512]);
    __syncthreads();

    short8 af[4], bfv[4];
#pragma unroll
    for (int i = 0; i < 4; ++i) {
      af[i]  = *(const short8*)&As[(wm * 64 + i * 16 + ml) * 32 + kq * 8];
      bfv[i] = *(const short8*)&Bs[(wn * 64 + i * 16 + ml) * 32 + kq * 8];
    }
#pragma unroll
    for (int i = 0; i < 4; ++i)
#pragma unroll
      for (int j = 0; j < 4; ++j)
        acc[i][j] = __builtin_amdgcn_mfma_f32_16x16x32_bf16(af[i], bfv[j], acc[i][j], 0, 0, 0);
    __syncthreads();
  }

  float scale[4][4];
  if (donorm) {
#pragma unroll
    for (int i = 0; i < 4; ++i) {
#pragma unroll
      for (int r = 0; r < 4; ++r) {
        float ss = 0.f;
#pragma unroll
        for (int j = 0; j < 4; ++j) ss = fmaf(acc[i][j][r], acc[i][j][r], ss);
        ss = rowsum16(ss);
        scale[i][r] = 1.0f / fmaxf(sqrtf(ss), 1e-12f);
      }
    }
  }

  const int row_base = m0 + wm * 64;
  const int col_base = n0 + wn * 64;
#pragma unroll
  for (int i = 0; i < 4; ++i) {
#pragma unroll
    for (int j = 0; j < 4; ++j) {
      int col = col_base + j * 16 + ml;
#pragma unroll
      for (int r = 0; r < 4; ++r) {
        int row = row_base + i * 16 + kq * 4 + r;
        float val = acc[i][j][r];
        if (donorm) val *= scale[i][r];
        if (act) val = sigmoidf_(val);
        Cw[(size_t)row * N + col] = val;
      }
    }
  }
}

// ---------------- beta projection (fp32, exact) ----------------
__global__ __launch_bounds__(256) void beta_kernel(
    const float* __restrict__ x, const float* __restrict__ Wb,
    const float* __restrict__ bb, float* __restrict__ beta_out)
{
  const int n = blockIdx.x;
  const int wid = threadIdx.x >> 6;
  const int lane = threadIdx.x & 63;
  const float* xr = x + (size_t)n * Cz;
  for (int h = wid; h < Hz; h += 4) {
    const float* wr = Wb + (size_t)h * Cz;
    float s = 0.f;
#pragma unroll 4
    for (int i = lane; i < Cz; i += 64) s = fmaf(xr[i], wr[i], s);
#pragma unroll
    for (int ofs = 32; ofs >= 1; ofs >>= 1) s += __shfl_xor(s, ofs);
    if (lane == 0) beta_out[(size_t)n * Hz + h] = sigmoidf_(s + bb[h]);
  }
}

// ---------------- delta-rule scan v4: async DMA -> LDS ring, manual vmcnt ------
// Per chain (b,h): 16 single-wave blocks own 4 rows each of the 64x64 state M
// (registers). q,k pre-normalized in the GEMM epilogue. Staging is pure
// global_load_lds DMA (no VGPRs -> compiler cannot sink it); ring of 4
// super-groups x 16 steps; asm s_waitcnt vmcnt(40) keeps ~2 super-groups of
// compute (~2000 cy) in flight ahead of consumption (covers ~900 cy HBM).
__global__ __launch_bounds__(64, 1) void scan_kernel(
    const float* __restrict__ q, const float* __restrict__ k,
    const float* __restrict__ v, const float* __restrict__ beta,
    float* __restrict__ o)
{
  __shared__ float4 qs[4][16][16];  // [slot][step][g]  16 KB
  __shared__ float4 ks[4][16][16];  // 16 KB
  __shared__ float  vs[4][16][4];   // [slot][step][row] 1 KB
  __shared__ float  bs[4][64];      // [slot][step] (first 16 used) 1 KB

  const int bid = blockIdx.x;     // 0..1023
  const int chain = bid & 63;     // (b,h); bid%8 -> XCD: row-groups share L2
  const int rg = bid >> 6;        // row group: rows rg*4 .. rg*4+3
  const int b = chain >> 4;
  const int h = chain & 15;
  const int lane = threadIdx.x;
  const int g  = lane & 15;       // column group: cols 4g..4g+3
  const int rr = lane >> 4;       // local row 0..3
  const int d0 = rg * 4;

  const size_t cbase = ((size_t)b * Tz) * Cz + (size_t)h * Dz;
  const float4* q4 = (const float4*)(q + cbase);
  const float4* k4 = (const float4*)(k + cbase);
  const float* vbase = v + cbase;
  const float* bbase = beta + ((size_t)b * Tz) * Hz + h;
  float* op = o + cbase + d0 + rr;   // per-lane output row
  const int C4 = Cz / 4;

  // per-lane DMA source offsets
  const int qstep = lane >> 4;      // step within a 4-step part
  const int vstep = lane >> 2;      // 0..15
  const int vrow  = lane & 3;
  const int bstep = lane & 15;

  auto prefetch_sg = [&](int slot, int t0) {
#pragma unroll
    for (int p = 0; p < 4; ++p) {
      int tq = t0 + p * 4 + qstep; tq = tq < Tz ? tq : Tz - 1;
      gload_lds16(q4 + (size_t)tq * C4 + g, &qs[slot][p * 4][0]);
      gload_lds16(k4 + (size_t)tq * C4 + g, &ks[slot][p * 4][0]);
    }
    int tv = t0 + vstep; tv = tv < Tz ? tv : Tz - 1;
    gload_lds4(vbase + (size_t)tv * Cz + d0 + vrow, &vs[slot][0][0]);
    int tb = t0 + bstep; tb = tb < Tz ? tb : Tz - 1;
    gload_lds4(bbase + (size_t)tb * Hz, &bs[slot][0]);
  };

  prefetch_sg(0, 0);
  prefetch_sg(1, 16);
  prefetch_sg(2, 32);

  float m0 = 0.f, m1 = 0.f, m2 = 0.f, m3 = 0.f;

  for (int n = 0; n < Tz / 16; ++n) {
    const int slot = n & 3;
    prefetch_sg((n + 3) & 3, (n + 3) * 16);
    // wait until this slot's 10 DMA loads retired (40 = 3 sg x 10 loads +
    // prev-iter 16 stores, minus forced early retire of one sg -> dist ~2 sg)
    asm volatile("s_waitcnt vmcnt(40)" ::: "memory");

    const int t0 = n * 16;
    float po[16];
#pragma unroll
    for (int s = 0; s < 16; ++s) {
      float4 kv = ks[slot][s][g];
      float4 qv = qs[slot][s][g];
      float vv = vs[slot][s][rr];
      float bb = bs[slot][s];
      // critical path: pk tree -> rowsum16 -> s -> m update
      float pk = fmaf(m0, kv.x, m1 * kv.y) + fmaf(m2, kv.z, m3 * kv.w);
      pk = rowsum16(pk);
      // po partial from PRE-update M; reduction deferred off-path
      po[s] = fmaf(m0, qv.x, m1 * qv.y) + fmaf(m2, qv.z, m3 * qv.w);
      float sc = bb * (vv - pk);
      m0 = fmaf(sc, kv.x, m0);
      m1 = fmaf(sc, kv.y, m1);
      m2 = fmaf(sc, kv.z, m2);
      m3 = fmaf(sc, kv.w, m3);
    }
#pragma unroll
    for (int s = 0; s < 16; ++s) {
      float pr = rowsum16(po[s]);
      if (g == 0) op[(size_t)(t0 + s) * Cz] = pr;  // lanes 0,16,32,48: 16B contig
    }
  }
}

// ---------------- gate*o -> bf16 ----------------
__global__ __launch_bounds__(256) void gate_mul_kernel(
    const float* __restrict__ gsig, const float* __restrict__ o,
    unsigned short* __restrict__ out, int n4)
{
  int i = blockIdx.x * blockDim.x + threadIdx.x;
  int stride = gridDim.x * blockDim.x;
  const float4* g4 = (const float4*)gsig;
  const float4* o4 = (const float4*)o;
  ushort4* out4 = (ushort4*)out;
  for (; i < n4; i += stride) {
    float4 gv = g4[i];
    float4 ov = o4[i];
    ushort4 u;
    u.x = f2bf(gv.x * ov.x);
    u.y = f2bf(gv.y * ov.y);
    u.z = f2bf(gv.z * ov.z);
    u.w = f2bf(gv.w * ov.w);
    out4[i] = u;
  }
}

extern "C" void kernel_launch(void* const* d_in, const int* in_sizes, int n_in,
                              void* d_out, int out_size, void* d_ws, size_t ws_size,
                              hipStream_t stream) {
  const float* x     = (const float*)d_in[0];
  const float* Wq    = (const float*)d_in[1];
  const float* Wk    = (const float*)d_in[2];
  const float* Wv    = (const float*)d_in[3];
  const float* Wbeta = (const float*)d_in[4];
  const float* bbeta = (const float*)d_in[5];
  const float* Wgate = (const float*)d_in[6];
  const float* Wo    = (const float*)d_in[7];
  float* out = (float*)d_out;

  char* ws = (char*)d_ws;
  size_t off = 0;
  auto alloc = [&](size_t bytes) -> char* {
    char* p = ws + off;
    off += (bytes + 255) & ~(size_t)255;
    return p;
  };
  unsigned short* xb  = (unsigned short*)alloc((size_t)NTOK * Cz * 2);
  unsigned short* Wqb = (unsigned short*)alloc((size_t)Cz * Cz * 2);
  unsigned short* Wkb = (unsigned short*)alloc((size_t)Cz * Cz * 2);
  unsigned short* Wvb = (unsigned short*)alloc((size_t)Cz * Cz * 2);
  unsigned short* Wgb = (unsigned short*)alloc((size_t)Cz * Cz * 2);
  unsigned short* Wob = (unsigned short*)alloc((size_t)Cz * Cz * 2);
  float* qf    = (float*)alloc((size_t)NTOK * Cz * 4);
  float* kf    = (float*)alloc((size_t)NTOK * Cz * 4);
  float* vf    = (float*)alloc((size_t)NTOK * Cz * 4);
  float* gf    = (float*)alloc((size_t)NTOK * Cz * 4);
  float* of    = (float*)alloc((size_t)NTOK * Cz * 4);
  float* betaf = (float*)alloc((size_t)NTOK * Hz * 4);
  unsigned short* ab = xb;  // reuse xb after projection GEMMs

  const int n4x = NTOK * Cz / 4;
  const int n4w = Cz * Cz / 4;

  cvt_bf16_kernel<<<dim3((n4x + 255) / 256), dim3(256), 0, stream>>>(x, xb, n4x);
  cvt_bf16_kernel<<<dim3((n4w + 255) / 256), dim3(256), 0, stream>>>(Wq, Wqb, n4w);
  cvt_bf16_kernel<<<dim3((n4w + 255) / 256), dim3(256), 0, stream>>>(Wk, Wkb, n4w);
  cvt_bf16_kernel<<<dim3((n4w + 255) / 256), dim3(256), 0, stream>>>(Wv, Wvb, n4w);
  cvt_bf16_kernel<<<dim3((n4w + 255) / 256), dim3(256), 0, stream>>>(Wgate, Wgb, n4w);
  cvt_bf16_kernel<<<dim3((n4w + 255) / 256), dim3(256), 0, stream>>>(Wo, Wob, n4w);

  // fused q,k,v,gate projections; q,k get l2norm epilogue, gate sigmoid
  gemm_bt_kernel<<<dim3(Cz / 128, NTOK / 128, 4), dim3(256), 0, stream>>>(
      xb, Wqb, Wkb, Wvb, Wgb, qf, kf, vf, gf, NTOK, Cz, Cz, 3, 3);

  beta_kernel<<<dim3(NTOK), dim3(256), 0, stream>>>(x, Wbeta, bbeta, betaf);

  scan_kernel<<<dim3(Bz * Hz * 16), dim3(64), 0, stream>>>(qf, kf, vf, betaf, of);

  gate_mul_kernel<<<dim3((n4x + 255) / 256), dim3(256), 0, stream>>>(gf, of, ab, n4x);

  gemm_bt_kernel<<<dim3(Cz / 128, NTOK / 128, 1), dim3(256), 0, stream>>>(
      ab, Wob, Wob, Wob, Wob, out, out, out, out, NTOK, Cz, Cz, -1, 0);
}

// Round 5
// 478.764 us; speedup vs baseline: 3.5268x; 1.1912x over previous
//
#include <hip/hip_runtime.h>
#include <cstdint>
#include <cstddef>

// Problem constants (B,T,C,H,D) = (4,2048,1024,16,64)
#define Bz 4
#define Tz 2048
#define Cz 1024
#define Hz 16
#define Dz 64
#define NTOK (Bz*Tz)   // 8192 tokens
#define CHL 32         // chunk length
#define NCH (Tz/CHL)   // 64 chunks per chain

typedef __attribute__((ext_vector_type(8))) short  short8;   // 8 x bf16 (4 VGPRs)
typedef __attribute__((ext_vector_type(4))) float  floatx4;  // MFMA accum

__device__ __forceinline__ unsigned short f2bf(float x) {
  union { float f; uint32_t u; } a; a.f = x;
  uint32_t r = a.u + 0x7fffu + ((a.u >> 16) & 1u);
  return (unsigned short)(r >> 16);
}
__device__ __forceinline__ float bf2f(unsigned short u) {
  union { uint32_t i; float f; } a; a.i = ((uint32_t)u) << 16; return a.f;
}
__device__ __forceinline__ float sigmoidf_(float z) {
  return 1.0f / (1.0f + __expf(-z));
}

// async global->LDS DMA (dest = wave-uniform LDS base + lane*size)
__device__ __forceinline__ void gload_lds16(const void* gptr, void* lptr) {
  __builtin_amdgcn_global_load_lds(
      (const __attribute__((address_space(1))) void*)(uintptr_t)gptr,
      (__attribute__((address_space(3))) void*)(uint32_t)(uintptr_t)lptr,
      16, 0, 0);
}

// ---- DPP 16-lane row reduction (VALU-speed, no DS pipe) ----
template<int CTRL>
__device__ __forceinline__ float dpp_addf(float x) {
  int y = __builtin_amdgcn_update_dpp(0, __float_as_int(x), CTRL, 0xF, 0xF, true);
  return x + __int_as_float(y);
}
__device__ __forceinline__ float rowsum16(float x) {
  x = dpp_addf<0xB1>(x);   // quad_perm xor1
  x = dpp_addf<0x4E>(x);   // quad_perm xor2
  x = dpp_addf<0x124>(x);  // row_ror:4
  x = dpp_addf<0x128>(x);  // row_ror:8
  return x;
}

union FragU { uint32_t u[4]; short8 s; };

// ---------------- fp32 -> bf16 convert ----------------
__global__ __launch_bounds__(256) void cvt_bf16_kernel(const float* __restrict__ in,
                                                       unsigned short* __restrict__ out,
                                                       int n4) {
  int i = blockIdx.x * blockDim.x + threadIdx.x;
  int stride = gridDim.x * blockDim.x;
  const float4* in4 = (const float4*)in;
  ushort4* out4 = (ushort4*)out;
  for (; i < n4; i += stride) {
    float4 f = in4[i];
    ushort4 u;
    u.x = f2bf(f.x); u.y = f2bf(f.y); u.z = f2bf(f.z); u.w = f2bf(f.w);
    out4[i] = u;
  }
}

// ---------------- bf16 MFMA GEMM: C[m,n] = sum_k A[m,k]*B[n,k] ----------------
// norm_mask bit z: per-64-col (per-head) l2 normalization in the epilogue.
__global__ __launch_bounds__(256) void gemm_bt_kernel(
    const unsigned short* __restrict__ A,
    const unsigned short* __restrict__ W0, const unsigned short* __restrict__ W1,
    const unsigned short* __restrict__ W2, const unsigned short* __restrict__ W3,
    float* __restrict__ O0, float* __restrict__ O1,
    float* __restrict__ O2, float* __restrict__ O3,
    int M, int N, int K, int nz_sigmoid, int norm_mask)
{
  const int z = blockIdx.z;
  const unsigned short* Bw = (z == 0) ? W0 : (z == 1) ? W1 : (z == 2) ? W2 : W3;
  float* Cw = (z == 0) ? O0 : (z == 1) ? O1 : (z == 2) ? O2 : O3;
  const bool act = (z == nz_sigmoid);
  const bool donorm = (norm_mask >> z) & 1;

  __shared__ unsigned short As[128 * 32];
  __shared__ unsigned short Bs[128 * 32];

  const int tid  = threadIdx.x;
  const int wid  = tid >> 6;
  const int lane = tid & 63;
  const int wm = wid & 1, wn = wid >> 1;
  const int m0 = blockIdx.y * 128;
  const int n0 = blockIdx.x * 128;

  const int srow = tid >> 2;
  const int scol = (tid & 3) * 8;

  floatx4 acc[4][4];
#pragma unroll
  for (int i = 0; i < 4; ++i)
#pragma unroll
    for (int j = 0; j < 4; ++j)
      acc[i][j] = floatx4{0.f, 0.f, 0.f, 0.f};

  const int ml = lane & 15;
  const int kq = lane >> 4;

  const unsigned short* Arow0 = A  + (size_t)(m0 + srow) * K + scol;
  const unsigned short* Arow1 = A  + (size_t)(m0 + 64 + srow) * K + scol;
  const unsigned short* Brow0 = Bw + (size_t)(n0 + srow) * K + scol;
  const unsigned short* Brow1 = Bw + (size_t)(n0 + 64 + srow) * K + scol;

  for (int kt = 0; kt < K; kt += 32) {
    gload_lds16(Arow0 + kt, &As[wid * 512]);
    gload_lds16(Arow1 + kt, &As[2048 + wid * 512]);
    gload_lds16(Brow0 + kt, &Bs[wid * 512]);
    gload_lds16(Brow1 + kt, &Bs[2048 + wid * 512]);
    __syncthreads();

    short8 af[4], bfv[4];
#pragma unroll
    for (int i = 0; i < 4; ++i) {
      af[i]  = *(const short8*)&As[(wm * 64 + i * 16 + ml) * 32 + kq * 8];
      bfv[i] = *(const short8*)&Bs[(wn * 64 + i * 16 + ml) * 32 + kq * 8];
    }
#pragma unroll
    for (int i = 0; i < 4; ++i)
#pragma unroll
      for (int j = 0; j < 4; ++j)
        acc[i][j] = __builtin_amdgcn_mfma_f32_16x16x32_bf16(af[i], bfv[j], acc[i][j], 0, 0, 0);
    __syncthreads();
  }

  float scale[4][4];
  if (donorm) {
#pragma unroll
    for (int i = 0; i < 4; ++i) {
#pragma unroll
      for (int r = 0; r < 4; ++r) {
        float ss = 0.f;
#pragma unroll
        for (int j = 0; j < 4; ++j) ss = fmaf(acc[i][j][r], acc[i][j][r], ss);
        ss = rowsum16(ss);
        scale[i][r] = 1.0f / fmaxf(sqrtf(ss), 1e-12f);
      }
    }
  }

  const int row_base = m0 + wm * 64;
  const int col_base = n0 + wn * 64;
#pragma unroll
  for (int i = 0; i < 4; ++i) {
#pragma unroll
    for (int j = 0; j < 4; ++j) {
      int col = col_base + j * 16 + ml;
#pragma unroll
      for (int r = 0; r < 4; ++r) {
        int row = row_base + i * 16 + kq * 4 + r;
        float val = acc[i][j][r];
        if (donorm) val *= scale[i][r];
        if (act) val = sigmoidf_(val);
        Cw[(size_t)row * N + col] = val;
      }
    }
  }
}

// ---------------- beta projection (fp32, exact) ----------------
__global__ __launch_bounds__(256) void beta_kernel(
    const float* __restrict__ x, const float* __restrict__ Wb,
    const float* __restrict__ bb, float* __restrict__ beta_out)
{
  const int n = blockIdx.x;
  const int wid = threadIdx.x >> 6;
  const int lane = threadIdx.x & 63;
  const float* xr = x + (size_t)n * Cz;
  for (int h = wid; h < Hz; h += 4) {
    const float* wr = Wb + (size_t)h * Cz;
    float s = 0.f;
#pragma unroll 4
    for (int i = lane; i < Cz; i += 64) s = fmaf(xr[i], wr[i], s);
#pragma unroll
    for (int ofs = 32; ofs >= 1; ofs >>= 1) s += __shfl_xor(s, ofs);
    if (lane == 0) beta_out[(size_t)n * Hz + h] = sigmoidf_(s + bb[h]);
  }
}

// ======== Chunked delta rule ========
// Phase 1 (parallel over 4096 chain-chunk blocks):
//   A[t][s] = beta_t (k_t.k_s), S_-[t][s] = tril(q_t.k_s,-1)
//   solve (I+A)[U|W] = diag(beta)[V|K] (forward substitution, fp32)
//   O_loc = S_- U  -> of;  Qt = Q - S_- W
//   Store (bf16, IN-PLACE into the dead q/k/v chunk slots this block owns):
//     qf slot: Qt[t][d] (idx t*64+d);  kf slot: W (idx 0..2047), K^T[e][t] (idx 2048..4095)
//     vf slot: U (idx 0..2047)
//   slot map: u16 idx -> global u16 addr ((tok0 + idx>>7)*Cz + h*64)*2 + (idx&127)
// Phase 2 (64 blocks = chains; serial over 64 chunks, M in persistent MFMA acc):
//   G = [Qt;W] (64x64); GEMM1 out = G (Mh+Ml)^T; rows<32: of += ; rows>=32: Yh
//   Z = U - Yh (hi/lo bf16); GEMM2: M += Z^T K  (acc registers)

__global__ __launch_bounds__(256) void deltachunk_phase1(
    float* __restrict__ qf, float* __restrict__ kf, float* __restrict__ vf,
    const float* __restrict__ betaf, float* __restrict__ of)
{
  __shared__ float Kf[32][64], Vf[32][64], Qf[32][64];
  __shared__ unsigned short Kb[2][32][32], Qb[2][32][32];  // eh-split bf16
  __shared__ float As[32][32];          // beta_t * (k_t.k_s) (all entries)
  __shared__ unsigned short Sb[32][32]; // strict-lower q_t.k_s bf16
  __shared__ unsigned short Us[32][64], Ws[32][64];
  __shared__ float bsh[32];

  const int bid = blockIdx.x;
  const int chain = bid & 63;          // chunk-major for L2 locality
  const int chunk = bid >> 6;
  const int b = chain >> 4, h = chain & 15;
  const int tid = threadIdx.x;
  const int wid = tid >> 6, lane = tid & 63;
  const int ml = lane & 15, kq = lane >> 4;

  const size_t tok0 = (size_t)b * Tz + (size_t)chunk * CHL;
  const float* qg = qf + tok0 * Cz + h * Dz;
  const float* kg = kf + tok0 * Cz + h * Dz;
  const float* vg = vf + tok0 * Cz + h * Dz;
  unsigned short* qfu = (unsigned short*)qf;
  unsigned short* kfu = (unsigned short*)kf;
  unsigned short* vfu = (unsigned short*)vf;

  // ---- stage chunk (32x64 fp32 x3) + bf16 copies ----
#pragma unroll
  for (int i = tid; i < 512; i += 256) {
    int r = i >> 4, c = (i & 15) * 4;
    float4 kv = *(const float4*)(kg + (size_t)r * Cz + c);
    float4 qv = *(const float4*)(qg + (size_t)r * Cz + c);
    float4 vv = *(const float4*)(vg + (size_t)r * Cz + c);
    *(float4*)&Kf[r][c] = kv;
    *(float4*)&Qf[r][c] = qv;
    *(float4*)&Vf[r][c] = vv;
    int eh = c >> 5, ep = c & 31;
    ushort4 kp, qp;
    kp.x = f2bf(kv.x); kp.y = f2bf(kv.y); kp.z = f2bf(kv.z); kp.w = f2bf(kv.w);
    qp.x = f2bf(qv.x); qp.y = f2bf(qv.y); qp.z = f2bf(qv.z); qp.w = f2bf(qv.w);
    *(ushort4*)&Kb[eh][r][ep] = kp;
    *(ushort4*)&Qb[eh][r][ep] = qp;
  }
  if (tid < 32) bsh[tid] = betaf[(tok0 + tid) * Hz + h];
  __syncthreads();

  // ---- A = K K^T, S = Q K^T (32x32 each; wave w -> tile (w&1, w>>1)) ----
  {
    const int tr = wid & 1, tc = wid >> 1;
    floatx4 accA = {0.f,0.f,0.f,0.f}, accS = {0.f,0.f,0.f,0.f};
#pragma unroll
    for (int eh = 0; eh < 2; ++eh) {
      short8 ka = *(const short8*)&Kb[eh][tr * 16 + ml][kq * 8];
      short8 kb = *(const short8*)&Kb[eh][tc * 16 + ml][kq * 8];
      short8 qa = *(const short8*)&Qb[eh][tr * 16 + ml][kq * 8];
      accA = __builtin_amdgcn_mfma_f32_16x16x32_bf16(ka, kb, accA, 0, 0, 0);
      accS = __builtin_amdgcn_mfma_f32_16x16x32_bf16(qa, kb, accS, 0, 0, 0);
    }
#pragma unroll
    for (int r = 0; r < 4; ++r) {
      int t = tr * 16 + kq * 4 + r;
      int s = tc * 16 + ml;
      As[t][s] = bsh[t] * accA[r];
      Sb[t][s] = (t > s) ? f2bf(accS[r]) : (unsigned short)0;
    }
  }
  __syncthreads();

  // ---- forward substitution: threads 0..127 = columns of [V|K] ----
  if (tid < 128) {
    const int j = tid;
    float x[32];
    if (j < 64) {
#pragma unroll
      for (int t = 0; t < 32; ++t) x[t] = bsh[t] * Vf[t][j];
    } else {
#pragma unroll
      for (int t = 0; t < 32; ++t) x[t] = bsh[t] * Kf[t][j - 64];
    }
#pragma unroll
    for (int t = 0; t < 31; ++t) {
      float xt = x[t];
#pragma unroll
      for (int s = t + 1; s < 32; ++s) x[s] = fmaf(-As[s][t], xt, x[s]);
    }
    if (j < 64) {
#pragma unroll
      for (int t = 0; t < 32; ++t) {
        unsigned short u = f2bf(x[t]);
        Us[t][j] = u;
        int idx = t * 64 + j;
        vfu[((tok0 + (size_t)(idx >> 7)) * Cz + h * Dz) * 2 + (idx & 127)] = u;
      }
    } else {
      const int d = j - 64;
#pragma unroll
      for (int t = 0; t < 32; ++t) {
        unsigned short u = f2bf(x[t]);
        Ws[t][d] = u;
        int idx = t * 64 + d;
        kfu[((tok0 + (size_t)(idx >> 7)) * Cz + h * Dz) * 2 + (idx & 127)] = u;
      }
    }
  }
  __syncthreads();

  // ---- O_loc = S_- U ; Qt = Q - S_- W   (wave w -> d cols w*16..w*16+15) ----
  {
    const int dw = wid * 16 + ml;
    FragU bu, bw;
#pragma unroll
    for (int r = 0; r < 4; ++r) {
      bu.u[r] = (uint32_t)Us[kq * 8 + 2 * r][dw] | ((uint32_t)Us[kq * 8 + 2 * r + 1][dw] << 16);
      bw.u[r] = (uint32_t)Ws[kq * 8 + 2 * r][dw] | ((uint32_t)Ws[kq * 8 + 2 * r + 1][dw] << 16);
    }
    floatx4 accO[2], accQ[2];
#pragma unroll
    for (int tt = 0; tt < 2; ++tt) { accO[tt] = floatx4{0.f,0.f,0.f,0.f}; accQ[tt] = floatx4{0.f,0.f,0.f,0.f}; }
#pragma unroll
    for (int tt = 0; tt < 2; ++tt) {
      short8 sa = *(const short8*)&Sb[tt * 16 + ml][kq * 8];
      accO[tt] = __builtin_amdgcn_mfma_f32_16x16x32_bf16(sa, bu.s, accO[tt], 0, 0, 0);
      accQ[tt] = __builtin_amdgcn_mfma_f32_16x16x32_bf16(sa, bw.s, accQ[tt], 0, 0, 0);
    }
#pragma unroll
    for (int tt = 0; tt < 2; ++tt) {
#pragma unroll
      for (int r = 0; r < 4; ++r) {
        int t = tt * 16 + kq * 4 + r;
        of[(tok0 + t) * Cz + h * Dz + dw] = accO[tt][r];
        unsigned short qt = f2bf(Qf[t][dw] - accQ[tt][r]);
        int idx = t * 64 + dw;
        qfu[((tok0 + (size_t)(idx >> 7)) * Cz + h * Dz) * 2 + (idx & 127)] = qt;
      }
    }
  }

  // ---- K^T bf16 -> kf slot idx 2048.. ----
  {
    int e = tid >> 2, tq = (tid & 3) * 8;
    unsigned short tmp[8];
#pragma unroll
    for (int i2 = 0; i2 < 8; ++i2) tmp[i2] = Kb[e >> 5][tq + i2][e & 31];
    int idx = 2048 + e * 32 + tq;
    *(uint4*)&kfu[((tok0 + (size_t)(idx >> 7)) * Cz + h * Dz) * 2 + (idx & 127)] = *(uint4*)tmp;
  }
}

__global__ __launch_bounds__(256) void deltachunk_phase2(
    const float* __restrict__ qf, const float* __restrict__ kf,
    const float* __restrict__ vf, float* __restrict__ of)
{
  __shared__ unsigned short Gb[2][64][32];   // [eh][i][e']  (Qt rows 0..31, W rows 32..63)
  __shared__ unsigned short Kt[64][32];      // [e][t]
  __shared__ unsigned short Mh[2][64][40], Ml[2][64][40];  // [eh][d][e'] pad
  __shared__ unsigned short Zh[64][40], Zl[64][40];        // [d][t] pad

  const int chain = blockIdx.x;
  const int b = chain >> 4, h = chain & 15;
  const int tid = threadIdx.x;
  const int wid = tid >> 6, lane = tid & 63;
  const int ml = lane & 15, kq = lane >> 4;
  const int iq = wid >> 1, jq = wid & 1;     // GEMM1 quadrant
  const int dq = wid >> 1, eq = wid & 1;     // GEMM2 quadrant

  const unsigned short* qfu = (const unsigned short*)qf;
  const unsigned short* kfu = (const unsigned short*)kf;
  const unsigned short* vfu = (const unsigned short*)vf;

  // zero M
  for (int i = tid; i < 2 * 64 * 40; i += 256) {
    (&Mh[0][0][0])[i] = 0; (&Ml[0][0][0])[i] = 0;
  }
  floatx4 mAcc[2][2];
#pragma unroll
  for (int a = 0; a < 2; ++a)
#pragma unroll
    for (int e = 0; e < 2; ++e) mAcc[a][e] = floatx4{0.f,0.f,0.f,0.f};

  auto slot_addr = [&](size_t tok0, int idx) -> size_t {
    return ((tok0 + (size_t)(idx >> 7)) * Cz + h * Dz) * 2 + (idx & 127);
  };

  // prologue: stage chunk 0
  {
    size_t t0 = (size_t)b * Tz;
    uint4 sq = *(const uint4*)&qfu[slot_addr(t0, tid * 8)];
    uint4 sw = *(const uint4*)&kfu[slot_addr(t0, tid * 8)];
    uint4 sk = *(const uint4*)&kfu[slot_addr(t0, 2048 + tid * 8)];
    int t = tid >> 3, d0 = (tid & 7) * 8, eh = d0 >> 5, e0 = d0 & 31;
    *(uint4*)&Gb[eh][t][e0] = sq;
    *(uint4*)&Gb[eh][32 + t][e0] = sw;
    int e = tid >> 2, t0q = (tid & 3) * 8;
    *(uint4*)&Kt[e][t0q] = sk;
  }
  __syncthreads();

  for (int c = 0; c < NCH; ++c) {
    const size_t tok0 = (size_t)b * Tz + (size_t)c * CHL;
    // --- epilogue inputs for THIS chunk (issue first: oldest in vmcnt queue) ---
    float pre[2][2][4];
    if (iq == 0) {
#pragma unroll
      for (int ti = 0; ti < 2; ++ti)
#pragma unroll
        for (int tj = 0; tj < 2; ++tj)
#pragma unroll
          for (int r = 0; r < 4; ++r)
            pre[ti][tj][r] = of[(tok0 + ti * 16 + kq * 4 + r) * Cz + h * Dz + jq * 32 + tj * 16 + ml];
    } else {
#pragma unroll
      for (int ti = 0; ti < 2; ++ti)
#pragma unroll
        for (int tj = 0; tj < 2; ++tj)
#pragma unroll
          for (int r = 0; r < 4; ++r) {
            int t = ti * 16 + kq * 4 + r, d = jq * 32 + tj * 16 + ml;
            pre[ti][tj][r] = bf2f(vfu[slot_addr(tok0, t * 64 + d)]);
          }
    }
    // --- stage loads for next chunk (kept outstanding across the compute) ---
    const int cn = (c + 1 < NCH) ? c + 1 : c;
    const size_t t0n = (size_t)b * Tz + (size_t)cn * CHL;
    uint4 sq = *(const uint4*)&qfu[slot_addr(t0n, tid * 8)];
    uint4 sw = *(const uint4*)&kfu[slot_addr(t0n, tid * 8)];
    uint4 sk = *(const uint4*)&kfu[slot_addr(t0n, 2048 + tid * 8)];

    __syncthreads();   // Gb/Kt(c) + Mh/Ml(c-1) visible

    // --- GEMM1: out = G * (Mh+Ml)^T  (quadrant iq,jq; 16 MFMA) ---
    floatx4 g1[2][2];
#pragma unroll
    for (int ti = 0; ti < 2; ++ti)
#pragma unroll
      for (int tj = 0; tj < 2; ++tj) g1[ti][tj] = floatx4{0.f,0.f,0.f,0.f};
#pragma unroll
    for (int eh = 0; eh < 2; ++eh) {
      short8 afr[2];
      afr[0] = *(const short8*)&Gb[eh][iq * 32 + 0 + ml][kq * 8];
      afr[1] = *(const short8*)&Gb[eh][iq * 32 + 16 + ml][kq * 8];
#pragma unroll
      for (int hl = 0; hl < 2; ++hl) {
#pragma unroll
        for (int tj = 0; tj < 2; ++tj) {
          short8 bfr = hl ? *(const short8*)&Ml[eh][jq * 32 + tj * 16 + ml][kq * 8]
                          : *(const short8*)&Mh[eh][jq * 32 + tj * 16 + ml][kq * 8];
          g1[0][tj] = __builtin_amdgcn_mfma_f32_16x16x32_bf16(afr[0], bfr, g1[0][tj], 0, 0, 0);
          g1[1][tj] = __builtin_amdgcn_mfma_f32_16x16x32_bf16(afr[1], bfr, g1[1][tj], 0, 0, 0);
        }
      }
    }
    // --- epilogue: O store / Z build ---
    if (iq == 0) {
#pragma unroll
      for (int ti = 0; ti < 2; ++ti)
#pragma unroll
        for (int tj = 0; tj < 2; ++tj)
#pragma unroll
          for (int r = 0; r < 4; ++r)
            of[(tok0 + ti * 16 + kq * 4 + r) * Cz + h * Dz + jq * 32 + tj * 16 + ml] =
                pre[ti][tj][r] + g1[ti][tj][r];
    } else {
#pragma unroll
      for (int ti = 0; ti < 2; ++ti)
#pragma unroll
        for (int tj = 0; tj < 2; ++tj)
#pragma unroll
          for (int r = 0; r < 4; ++r) {
            int t = ti * 16 + kq * 4 + r, d = jq * 32 + tj * 16 + ml;
            float z = pre[ti][tj][r] - g1[ti][tj][r];
            unsigned short zh = f2bf(z);
            Zh[d][t] = zh;
            Zl[d][t] = f2bf(z - bf2f(zh));
          }
    }
    __syncthreads();   // Zh/Zl visible

    // --- GEMM2: M += Z^T K  (quadrant dq,eq; 8 MFMA into persistent acc) ---
    {
      short8 kfr[2];
      kfr[0] = *(const short8*)&Kt[eq * 32 + 0 + ml][kq * 8];
      kfr[1] = *(const short8*)&Kt[eq * 32 + 16 + ml][kq * 8];
#pragma unroll
      for (int hl = 0; hl < 2; ++hl) {
#pragma unroll
        for (int dt = 0; dt < 2; ++dt) {
          short8 afr = hl ? *(const short8*)&Zl[dq * 32 + dt * 16 + ml][kq * 8]
                          : *(const short8*)&Zh[dq * 32 + dt * 16 + ml][kq * 8];
          mAcc[dt][0] = __builtin_amdgcn_mfma_f32_16x16x32_bf16(afr, kfr[0], mAcc[dt][0], 0, 0, 0);
          mAcc[dt][1] = __builtin_amdgcn_mfma_f32_16x16x32_bf16(afr, kfr[1], mAcc[dt][1], 0, 0, 0);
        }
      }
      // write back hi/lo M
#pragma unroll
      for (int dt = 0; dt < 2; ++dt)
#pragma unroll
        for (int et = 0; et < 2; ++et)
#pragma unroll
          for (int r = 0; r < 4; ++r) {
            int d = dq * 32 + dt * 16 + kq * 4 + r;
            int ec = et * 16 + ml;
            float mv = mAcc[dt][et][r];
            unsigned short mh = f2bf(mv);
            Mh[eq][d][ec] = mh;
            Ml[eq][d][ec] = f2bf(mv - bf2f(mh));
          }
    }
    __syncthreads();   // GEMM2 LDS reads done; Mh/Ml written

    // --- stage next chunk into Gb/Kt (loads issued ~whole chunk ago) ---
    {
      int t = tid >> 3, d0 = (tid & 7) * 8, eh = d0 >> 5, e0 = d0 & 31;
      *(uint4*)&Gb[eh][t][e0] = sq;
      *(uint4*)&Gb[eh][32 + t][e0] = sw;
      int e = tid >> 2, t0q = (tid & 3) * 8;
      *(uint4*)&Kt[e][t0q] = sk;
    }
  }
}

// ---------------- gate*o -> bf16 ----------------
__global__ __launch_bounds__(256) void gate_mul_kernel(
    const float* __restrict__ gsig, const float* __restrict__ o,
    unsigned short* __restrict__ out, int n4)
{
  int i = blockIdx.x * blockDim.x + threadIdx.x;
  int stride = gridDim.x * blockDim.x;
  const float4* g4 = (const float4*)gsig;
  const float4* o4 = (const float4*)o;
  ushort4* out4 = (ushort4*)out;
  for (; i < n4; i += stride) {
    float4 gv = g4[i];
    float4 ov = o4[i];
    ushort4 u;
    u.x = f2bf(gv.x * ov.x);
    u.y = f2bf(gv.y * ov.y);
    u.z = f2bf(gv.z * ov.z);
    u.w = f2bf(gv.w * ov.w);
    out4[i] = u;
  }
}

extern "C" void kernel_launch(void* const* d_in, const int* in_sizes, int n_in,
                              void* d_out, int out_size, void* d_ws, size_t ws_size,
                              hipStream_t stream) {
  const float* x     = (const float*)d_in[0];
  const float* Wq    = (const float*)d_in[1];
  const float* Wk    = (const float*)d_in[2];
  const float* Wv    = (const float*)d_in[3];
  const float* Wbeta = (const float*)d_in[4];
  const float* bbeta = (const float*)d_in[5];
  const float* Wgate = (const float*)d_in[6];
  const float* Wo    = (const float*)d_in[7];
  float* out = (float*)d_out;

  char* ws = (char*)d_ws;
  size_t off = 0;
  auto alloc = [&](size_t bytes) -> char* {
    char* p = ws + off;
    off += (bytes + 255) & ~(size_t)255;
    return p;
  };
  unsigned short* xb  = (unsigned short*)alloc((size_t)NTOK * Cz * 2);
  unsigned short* Wqb = (unsigned short*)alloc((size_t)Cz * Cz * 2);
  unsigned short* Wkb = (unsigned short*)alloc((size_t)Cz * Cz * 2);
  unsigned short* Wvb = (unsigned short*)alloc((size_t)Cz * Cz * 2);
  unsigned short* Wgb = (unsigned short*)alloc((size_t)Cz * Cz * 2);
  unsigned short* Wob = (unsigned short*)alloc((size_t)Cz * Cz * 2);
  float* qf    = (float*)alloc((size_t)NTOK * Cz * 4);
  float* kf    = (float*)alloc((size_t)NTOK * Cz * 4);
  float* vf    = (float*)alloc((size_t)NTOK * Cz * 4);
  float* gf    = (float*)alloc((size_t)NTOK * Cz * 4);
  float* of    = (float*)alloc((size_t)NTOK * Cz * 4);
  float* betaf = (float*)alloc((size_t)NTOK * Hz * 4);
  unsigned short* ab = xb;  // reuse xb after projection GEMMs

  const int n4x = NTOK * Cz / 4;
  const int n4w = Cz * Cz / 4;

  cvt_bf16_kernel<<<dim3((n4x + 255) / 256), dim3(256), 0, stream>>>(x, xb, n4x);
  cvt_bf16_kernel<<<dim3((n4w + 255) / 256), dim3(256), 0, stream>>>(Wq, Wqb, n4w);
  cvt_bf16_kernel<<<dim3((n4w + 255) / 256), dim3(256), 0, stream>>>(Wk, Wkb, n4w);
  cvt_bf16_kernel<<<dim3((n4w + 255) / 256), dim3(256), 0, stream>>>(Wv, Wvb, n4w);
  cvt_bf16_kernel<<<dim3((n4w + 255) / 256), dim3(256), 0, stream>>>(Wgate, Wgb, n4w);
  cvt_bf16_kernel<<<dim3((n4w + 255) / 256), dim3(256), 0, stream>>>(Wo, Wob, n4w);

  // fused q,k,v,gate projections; q,k get l2norm epilogue, gate sigmoid
  gemm_bt_kernel<<<dim3(Cz / 128, NTOK / 128, 4), dim3(256), 0, stream>>>(
      xb, Wqb, Wkb, Wvb, Wgb, qf, kf, vf, gf, NTOK, Cz, Cz, 3, 3);

  beta_kernel<<<dim3(NTOK), dim3(256), 0, stream>>>(x, Wbeta, bbeta, betaf);

  deltachunk_phase1<<<dim3(64 * NCH), dim3(256), 0, stream>>>(qf, kf, vf, betaf, of);
  deltachunk_phase2<<<dim3(Bz * Hz), dim3(256), 0, stream>>>(qf, kf, vf, of);

  gate_mul_kernel<<<dim3((n4x + 255) / 256), dim3(256), 0, stream>>>(gf, of, ab, n4x);

  gemm_bt_kernel<<<dim3(Cz / 128, NTOK / 128, 1), dim3(256), 0, stream>>>(
      ab, Wob, Wob, Wob, Wob, out, out, out, out, NTOK, Cz, Cz, -1, 0);
}

// Round 6
// 435.761 us; speedup vs baseline: 3.8748x; 1.0987x over previous
//
#include <hip/hip_runtime.h>
#include <cstdint>
#include <cstddef>

// Problem constants (B,T,C,H,D) = (4,2048,1024,16,64)
#define Bz 4
#define Tz 2048
#define Cz 1024
#define Hz 16
#define Dz 64
#define NTOK (Bz*Tz)   // 8192 tokens
#define CHL 32         // chunk length
#define NCH (Tz/CHL)   // 64 chunks per chain

typedef __attribute__((ext_vector_type(8))) short  short8;   // 8 x bf16 (4 VGPRs)
typedef __attribute__((ext_vector_type(4))) float  floatx4;  // MFMA accum

__device__ __forceinline__ unsigned short f2bf(float x) {
  union { float f; uint32_t u; } a; a.f = x;
  uint32_t r = a.u + 0x7fffu + ((a.u >> 16) & 1u);
  return (unsigned short)(r >> 16);
}
__device__ __forceinline__ float bf2f(unsigned short u) {
  union { uint32_t i; float f; } a; a.i = ((uint32_t)u) << 16; return a.f;
}
__device__ __forceinline__ float sigmoidf_(float z) {
  return 1.0f / (1.0f + __expf(-z));
}

// async global->LDS DMA (dest = wave-uniform LDS base + lane*size)
__device__ __forceinline__ void gload_lds16(const void* gptr, void* lptr) {
  __builtin_amdgcn_global_load_lds(
      (const __attribute__((address_space(1))) void*)(uintptr_t)gptr,
      (__attribute__((address_space(3))) void*)(uint32_t)(uintptr_t)lptr,
      16, 0, 0);
}

// ---- DPP 16-lane row reduction ----
template<int CTRL>
__device__ __forceinline__ float dpp_addf(float x) {
  int y = __builtin_amdgcn_update_dpp(0, __float_as_int(x), CTRL, 0xF, 0xF, true);
  return x + __int_as_float(y);
}
__device__ __forceinline__ float rowsum16(float x) {
  x = dpp_addf<0xB1>(x);   // quad_perm xor1
  x = dpp_addf<0x4E>(x);   // quad_perm xor2
  x = dpp_addf<0x124>(x);  // row_ror:4
  x = dpp_addf<0x128>(x);  // row_ror:8
  return x;
}

union FragU { uint32_t u[4]; short8 s; };

// ---------------- fp32 -> bf16 converts ----------------
__global__ __launch_bounds__(256) void cvt_bf16_kernel(const float* __restrict__ in,
                                                       unsigned short* __restrict__ out,
                                                       int n4) {
  int i = blockIdx.x * blockDim.x + threadIdx.x;
  int stride = gridDim.x * blockDim.x;
  const float4* in4 = (const float4*)in;
  ushort4* out4 = (ushort4*)out;
  for (; i < n4; i += stride) {
    float4 f = in4[i];
    ushort4 u;
    u.x = f2bf(f.x); u.y = f2bf(f.y); u.z = f2bf(f.z); u.w = f2bf(f.w);
    out4[i] = u;
  }
}

__global__ __launch_bounds__(256) void cvt_w5_kernel(
    const float* __restrict__ s0, const float* __restrict__ s1,
    const float* __restrict__ s2, const float* __restrict__ s3,
    const float* __restrict__ s4,
    unsigned short* __restrict__ d0, unsigned short* __restrict__ d1,
    unsigned short* __restrict__ d2, unsigned short* __restrict__ d3,
    unsigned short* __restrict__ d4, int n4)
{
  const int w = blockIdx.y;
  const float* s = (w == 0) ? s0 : (w == 1) ? s1 : (w == 2) ? s2 : (w == 3) ? s3 : s4;
  unsigned short* d = (w == 0) ? d0 : (w == 1) ? d1 : (w == 2) ? d2 : (w == 3) ? d3 : d4;
  int i = blockIdx.x * blockDim.x + threadIdx.x;
  if (i < n4) {
    float4 f = ((const float4*)s)[i];
    ushort4 u;
    u.x = f2bf(f.x); u.y = f2bf(f.y); u.z = f2bf(f.z); u.w = f2bf(f.w);
    ((ushort4*)d)[i] = u;
  }
}

// ---------------- bf16 MFMA GEMM: C[m,n] = sum_k A[m,k]*B[n,k] ----------------
// norm_mask bit z: per-64-col (per-head) l2 normalization in the epilogue.
// out_bf16: store bf16 (ushort) instead of fp32.
__global__ __launch_bounds__(256) void gemm_bt_kernel(
    const unsigned short* __restrict__ A,
    const unsigned short* __restrict__ W0, const unsigned short* __restrict__ W1,
    const unsigned short* __restrict__ W2, const unsigned short* __restrict__ W3,
    void* __restrict__ O0, void* __restrict__ O1,
    void* __restrict__ O2, void* __restrict__ O3,
    int M, int N, int K, int nz_sigmoid, int norm_mask, int out_bf16)
{
  const int z = blockIdx.z;
  const unsigned short* Bw = (z == 0) ? W0 : (z == 1) ? W1 : (z == 2) ? W2 : W3;
  void* Cw = (z == 0) ? O0 : (z == 1) ? O1 : (z == 2) ? O2 : O3;
  const bool act = (z == nz_sigmoid);
  const bool donorm = (norm_mask >> z) & 1;

  __shared__ unsigned short As[128 * 32];
  __shared__ unsigned short Bs[128 * 32];

  const int tid  = threadIdx.x;
  const int wid  = tid >> 6;
  const int lane = tid & 63;
  const int wm = wid & 1, wn = wid >> 1;
  const int m0 = blockIdx.y * 128;
  const int n0 = blockIdx.x * 128;

  const int srow = tid >> 2;
  const int scol = (tid & 3) * 8;

  floatx4 acc[4][4];
#pragma unroll
  for (int i = 0; i < 4; ++i)
#pragma unroll
    for (int j = 0; j < 4; ++j)
      acc[i][j] = floatx4{0.f, 0.f, 0.f, 0.f};

  const int ml = lane & 15;
  const int kq = lane >> 4;

  const unsigned short* Arow0 = A  + (size_t)(m0 + srow) * K + scol;
  const unsigned short* Arow1 = A  + (size_t)(m0 + 64 + srow) * K + scol;
  const unsigned short* Brow0 = Bw + (size_t)(n0 + srow) * K + scol;
  const unsigned short* Brow1 = Bw + (size_t)(n0 + 64 + srow) * K + scol;

  for (int kt = 0; kt < K; kt += 32) {
    gload_lds16(Arow0 + kt, &As[wid * 512]);
    gload_lds16(Arow1 + kt, &As[2048 + wid * 512]);
    gload_lds16(Brow0 + kt, &Bs[wid * 512]);
    gload_lds16(Brow1 + kt, &Bs[2048 + wid * 512]);
    __syncthreads();

    short8 af[4], bfv[4];
#pragma unroll
    for (int i = 0; i < 4; ++i) {
      af[i]  = *(const short8*)&As[(wm * 64 + i * 16 + ml) * 32 + kq * 8];
      bfv[i] = *(const short8*)&Bs[(wn * 64 + i * 16 + ml) * 32 + kq * 8];
    }
#pragma unroll
    for (int i = 0; i < 4; ++i)
#pragma unroll
      for (int j = 0; j < 4; ++j)
        acc[i][j] = __builtin_amdgcn_mfma_f32_16x16x32_bf16(af[i], bfv[j], acc[i][j], 0, 0, 0);
    __syncthreads();
  }

  float scale[4][4];
  if (donorm) {
#pragma unroll
    for (int i = 0; i < 4; ++i) {
#pragma unroll
      for (int r = 0; r < 4; ++r) {
        float ss = 0.f;
#pragma unroll
        for (int j = 0; j < 4; ++j) ss = fmaf(acc[i][j][r], acc[i][j][r], ss);
        ss = rowsum16(ss);
        scale[i][r] = 1.0f / fmaxf(sqrtf(ss), 1e-12f);
      }
    }
  }

  const int row_base = m0 + wm * 64;
  const int col_base = n0 + wn * 64;
#pragma unroll
  for (int i = 0; i < 4; ++i) {
#pragma unroll
    for (int j = 0; j < 4; ++j) {
      int col = col_base + j * 16 + ml;
#pragma unroll
      for (int r = 0; r < 4; ++r) {
        int row = row_base + i * 16 + kq * 4 + r;
        float val = acc[i][j][r];
        if (donorm) val *= scale[i][r];
        if (act) val = sigmoidf_(val);
        if (out_bf16) ((unsigned short*)Cw)[(size_t)row * N + col] = f2bf(val);
        else          ((float*)Cw)[(size_t)row * N + col] = val;
      }
    }
  }
}

// ---------------- beta projection (fp32, exact) ----------------
__global__ __launch_bounds__(256) void beta_kernel(
    const float* __restrict__ x, const float* __restrict__ Wb,
    const float* __restrict__ bb, float* __restrict__ beta_out)
{
  const int n = blockIdx.x;
  const int wid = threadIdx.x >> 6;
  const int lane = threadIdx.x & 63;
  const float* xr = x + (size_t)n * Cz;
  for (int h = wid; h < Hz; h += 4) {
    const float* wr = Wb + (size_t)h * Cz;
    float s = 0.f;
#pragma unroll 4
    for (int i = lane; i < Cz; i += 64) s = fmaf(xr[i], wr[i], s);
#pragma unroll
    for (int ofs = 32; ofs >= 1; ofs >>= 1) s += __shfl_xor(s, ofs);
    if (lane == 0) beta_out[(size_t)n * Hz + h] = sigmoidf_(s + bb[h]);
  }
}

// ======== Chunked delta rule ========
// Phase 1 (4096 blocks = chain x chunk), bf16 q,k,v inputs:
//   A[t][s]=beta_t(k_t.k_s), S_-=tril(q k^T,-1); solve (I+A)[U|W]=diag(beta)[V|K] fp32;
//   of = S_- U;  Qt = Q - S_- W.  Write compact bf16: qtb=Qt[t][d], wbuf=W[t][d],
//   ubuf=U[t][d], ktb=K^T[e][t]  (index base (chain*NCH+chunk)*2048).
// Phase 2 (64 blocks = chains): per chunk GEMM1 out=G(Mh+Ml)^T (G=[Qt;W]);
//   rows<32: of += ; rows>=32: Z=U-Yh (hi/lo); GEMM2 M += Z^T K (persistent acc).

__global__ __launch_bounds__(256) void deltachunk_phase1(
    const unsigned short* __restrict__ qb, const unsigned short* __restrict__ kb,
    const unsigned short* __restrict__ vb, const float* __restrict__ betaf,
    float* __restrict__ of,
    unsigned short* __restrict__ qtb, unsigned short* __restrict__ wbuf,
    unsigned short* __restrict__ ubuf, unsigned short* __restrict__ ktb)
{
  __shared__ unsigned short Kb[32][72], Qb[32][72], Vb[32][72];
  __shared__ float As[32][33];
  __shared__ unsigned short Sb[32][40];
  __shared__ unsigned short Us[32][72], Ws[32][72], Qts[32][72];
  __shared__ float bsh[32];

  const int bid = blockIdx.x;
  const int chain = bid & 63;          // chunk-major dispatch for L2 locality
  const int chunk = bid >> 6;
  const int b = chain >> 4, h = chain & 15;
  const int tid = threadIdx.x;
  const int wid = tid >> 6, lane = tid & 63;
  const int ml = lane & 15, kq = lane >> 4;

  const size_t tok0 = (size_t)b * Tz + (size_t)chunk * CHL;
  const size_t cb = ((size_t)chain * NCH + chunk) * 2048;  // compact base (u16)

  // ---- stage chunk: 32x64 bf16 x3, one uint4 per thread per array ----
  {
    const int row = tid >> 3, c8 = (tid & 7) * 8;
    const size_t ga = (tok0 + row) * Cz + h * Dz + c8;
    *(uint4*)&Qb[row][c8] = *(const uint4*)&qb[ga];
    *(uint4*)&Kb[row][c8] = *(const uint4*)&kb[ga];
    *(uint4*)&Vb[row][c8] = *(const uint4*)&vb[ga];
  }
  if (tid < 32) bsh[tid] = betaf[(tok0 + tid) * Hz + h];
  __syncthreads();

  // ---- A = K K^T, S = Q K^T (wave w -> tile (w&1, w>>1)) ----
  {
    const int tr = wid & 1, tc = wid >> 1;
    floatx4 accA = {0.f,0.f,0.f,0.f}, accS = {0.f,0.f,0.f,0.f};
#pragma unroll
    for (int eh = 0; eh < 2; ++eh) {
      short8 ka = *(const short8*)&Kb[tr * 16 + ml][eh * 32 + kq * 8];
      short8 kbf = *(const short8*)&Kb[tc * 16 + ml][eh * 32 + kq * 8];
      short8 qa = *(const short8*)&Qb[tr * 16 + ml][eh * 32 + kq * 8];
      accA = __builtin_amdgcn_mfma_f32_16x16x32_bf16(ka, kbf, accA, 0, 0, 0);
      accS = __builtin_amdgcn_mfma_f32_16x16x32_bf16(qa, kbf, accS, 0, 0, 0);
    }
#pragma unroll
    for (int r = 0; r < 4; ++r) {
      int t = tr * 16 + kq * 4 + r;
      int s = tc * 16 + ml;
      As[t][s] = bsh[t] * accA[r];
      Sb[t][s] = (t > s) ? f2bf(accS[r]) : (unsigned short)0;
    }
  }
  __syncthreads();

  // ---- forward substitution: threads 0..127 = columns of [V|K], fp32 ----
  if (tid < 128) {
    const int j = tid;
    float x[32];
    if (j < 64) {
#pragma unroll
      for (int t = 0; t < 32; ++t) x[t] = bsh[t] * bf2f(Vb[t][j]);
    } else {
#pragma unroll
      for (int t = 0; t < 32; ++t) x[t] = bsh[t] * bf2f(Kb[t][j - 64]);
    }
#pragma unroll
    for (int t = 0; t < 31; ++t) {
      float xt = x[t];
#pragma unroll
      for (int s = t + 1; s < 32; ++s) x[s] = fmaf(-As[s][t], xt, x[s]);
    }
    if (j < 64) {
#pragma unroll
      for (int t = 0; t < 32; ++t) Us[t][j] = f2bf(x[t]);
    } else {
#pragma unroll
      for (int t = 0; t < 32; ++t) Ws[t][j - 64] = f2bf(x[t]);
    }
  }
  __syncthreads();

  // ---- O_loc = S_- U -> of ; Qt = Q - S_- W -> Qts (wave w: d cols w*16..) ----
  {
    const int dw = wid * 16 + ml;
    FragU bu, bw;
#pragma unroll
    for (int r = 0; r < 4; ++r) {
      bu.u[r] = (uint32_t)Us[kq * 8 + 2 * r][dw] | ((uint32_t)Us[kq * 8 + 2 * r + 1][dw] << 16);
      bw.u[r] = (uint32_t)Ws[kq * 8 + 2 * r][dw] | ((uint32_t)Ws[kq * 8 + 2 * r + 1][dw] << 16);
    }
    floatx4 accO[2], accQ[2];
#pragma unroll
    for (int tt = 0; tt < 2; ++tt) { accO[tt] = floatx4{0.f,0.f,0.f,0.f}; accQ[tt] = floatx4{0.f,0.f,0.f,0.f}; }
#pragma unroll
    for (int tt = 0; tt < 2; ++tt) {
      short8 sa = *(const short8*)&Sb[tt * 16 + ml][kq * 8];
      accO[tt] = __builtin_amdgcn_mfma_f32_16x16x32_bf16(sa, bu.s, accO[tt], 0, 0, 0);
      accQ[tt] = __builtin_amdgcn_mfma_f32_16x16x32_bf16(sa, bw.s, accQ[tt], 0, 0, 0);
    }
#pragma unroll
    for (int tt = 0; tt < 2; ++tt) {
#pragma unroll
      for (int r = 0; r < 4; ++r) {
        int t = tt * 16 + kq * 4 + r;
        of[(tok0 + t) * Cz + h * Dz + dw] = accO[tt][r];
        Qts[t][dw] = f2bf(bf2f(Qb[t][dw]) - accQ[tt][r]);
      }
    }
  }

  // ---- K^T gather (no dependence on Qts; before barrier) ----
  unsigned short ktmp[8];
  {
    const int e = tid >> 2, tq = (tid & 3) * 8;
#pragma unroll
    for (int i2 = 0; i2 < 8; ++i2) ktmp[i2] = Kb[tq + i2][e];
  }
  __syncthreads();

  // ---- compact coalesced stores ----
  {
    const int row = tid >> 3, c8 = (tid & 7) * 8;
    const size_t o16 = cb + (size_t)row * 64 + c8;
    *(uint4*)&qtb[o16]  = *(const uint4*)&Qts[row][c8];
    *(uint4*)&wbuf[o16] = *(const uint4*)&Ws[row][c8];
    *(uint4*)&ubuf[o16] = *(const uint4*)&Us[row][c8];
    const int e = tid >> 2, tq = (tid & 3) * 8;
    *(uint4*)&ktb[cb + (size_t)e * 32 + tq] = *(const uint4*)ktmp;
  }
}

__global__ __launch_bounds__(256) void deltachunk_phase2(
    const unsigned short* __restrict__ qtb, const unsigned short* __restrict__ wbuf,
    const unsigned short* __restrict__ ubuf, const unsigned short* __restrict__ ktb,
    float* __restrict__ of)
{
  __shared__ unsigned short Gb[64][72];    // rows 0..31 Qt, 32..63 W  [i][e]
  __shared__ unsigned short Kts[64][40];   // [e][t]
  __shared__ unsigned short Ub[32][72];    // [t][d]
  __shared__ unsigned short Mh[64][72], Ml[64][72];   // [d][e] hi/lo
  __shared__ unsigned short Zh[64][40], Zl[64][40];   // [d][t] hi/lo

  const int chain = blockIdx.x;
  const int b = chain >> 4, h = chain & 15;
  const int tid = threadIdx.x;
  const int wid = tid >> 6, lane = tid & 63;
  const int ml = lane & 15, kq = lane >> 4;
  const int iq = wid >> 1, jq = wid & 1;     // GEMM1 quadrant
  const int dq = wid >> 1, eq = wid & 1;     // GEMM2 quadrant

  for (int i = tid; i < 64 * 72; i += 256) { (&Mh[0][0])[i] = 0; (&Ml[0][0])[i] = 0; }
  floatx4 mAcc[2][2];
#pragma unroll
  for (int a = 0; a < 2; ++a)
#pragma unroll
    for (int e = 0; e < 2; ++e) mAcc[a][e] = floatx4{0.f,0.f,0.f,0.f};

  const int grow = tid >> 3, gc8 = (tid & 7) * 8;   // G/U staging coords
  const int ke = tid >> 2,  kt8 = (tid & 3) * 8;    // Kt staging coords

  // prologue: stage chunk 0
  {
    const size_t cb = (size_t)chain * NCH * 2048;
    *(uint4*)&Gb[grow][gc8]      = *(const uint4*)&qtb[cb + (size_t)grow * 64 + gc8];
    *(uint4*)&Gb[32 + grow][gc8] = *(const uint4*)&wbuf[cb + (size_t)grow * 64 + gc8];
    *(uint4*)&Ub[grow][gc8]      = *(const uint4*)&ubuf[cb + (size_t)grow * 64 + gc8];
    *(uint4*)&Kts[ke][kt8]       = *(const uint4*)&ktb[cb + (size_t)ke * 32 + kt8];
  }
  __syncthreads();

  for (int c = 0; c < NCH; ++c) {
    const size_t tok0 = (size_t)b * Tz + (size_t)c * CHL;
    // of pre-read for this chunk (iq==0 waves; stays in flight across barrier)
    float pre[2][2][4];
    if (iq == 0) {
#pragma unroll
      for (int ti = 0; ti < 2; ++ti)
#pragma unroll
        for (int tj = 0; tj < 2; ++tj)
#pragma unroll
          for (int r = 0; r < 4; ++r)
            pre[ti][tj][r] = of[(tok0 + ti * 16 + kq * 4 + r) * Cz + h * Dz + jq * 32 + tj * 16 + ml];
    }
    // next-chunk staging loads into regs (outstanding across the compute)
    const int cn = (c + 1 < NCH) ? c + 1 : c;
    const size_t cbn = ((size_t)chain * NCH + cn) * 2048;
    uint4 sq = *(const uint4*)&qtb[cbn + (size_t)grow * 64 + gc8];
    uint4 sw = *(const uint4*)&wbuf[cbn + (size_t)grow * 64 + gc8];
    uint4 su = *(const uint4*)&ubuf[cbn + (size_t)grow * 64 + gc8];
    uint4 sk = *(const uint4*)&ktb[cbn + (size_t)ke * 32 + kt8];

    __syncthreads();   // Gb/Kts/Ub(c) + Mh/Ml(c-1) visible

    // --- GEMM1: out = G (Mh+Ml)^T, quadrant (iq,jq), 16 MFMA ---
    floatx4 g1[2][2];
#pragma unroll
    for (int ti = 0; ti < 2; ++ti)
#pragma unroll
      for (int tj = 0; tj < 2; ++tj) g1[ti][tj] = floatx4{0.f,0.f,0.f,0.f};
#pragma unroll
    for (int eh = 0; eh < 2; ++eh) {
      short8 afr[2];
      afr[0] = *(const short8*)&Gb[iq * 32 + 0  + ml][eh * 32 + kq * 8];
      afr[1] = *(const short8*)&Gb[iq * 32 + 16 + ml][eh * 32 + kq * 8];
#pragma unroll
      for (int hl = 0; hl < 2; ++hl) {
#pragma unroll
        for (int tj = 0; tj < 2; ++tj) {
          short8 bfr = hl ? *(const short8*)&Ml[jq * 32 + tj * 16 + ml][eh * 32 + kq * 8]
                          : *(const short8*)&Mh[jq * 32 + tj * 16 + ml][eh * 32 + kq * 8];
          g1[0][tj] = __builtin_amdgcn_mfma_f32_16x16x32_bf16(afr[0], bfr, g1[0][tj], 0, 0, 0);
          g1[1][tj] = __builtin_amdgcn_mfma_f32_16x16x32_bf16(afr[1], bfr, g1[1][tj], 0, 0, 0);
        }
      }
    }
    // --- epilogue: O store / Z build ---
    if (iq == 0) {
#pragma unroll
      for (int ti = 0; ti < 2; ++ti)
#pragma unroll
        for (int tj = 0; tj < 2; ++tj)
#pragma unroll
          for (int r = 0; r < 4; ++r)
            of[(tok0 + ti * 16 + kq * 4 + r) * Cz + h * Dz + jq * 32 + tj * 16 + ml] =
                pre[ti][tj][r] + g1[ti][tj][r];
    } else {
#pragma unroll
      for (int ti = 0; ti < 2; ++ti)
#pragma unroll
        for (int tj = 0; tj < 2; ++tj)
#pragma unroll
          for (int r = 0; r < 4; ++r) {
            int t = ti * 16 + kq * 4 + r, d = jq * 32 + tj * 16 + ml;
            float z = bf2f(Ub[t][d]) - g1[ti][tj][r];
            unsigned short zh = f2bf(z);
            Zh[d][t] = zh;
            Zl[d][t] = f2bf(z - bf2f(zh));
          }
    }
    __syncthreads();   // Zh/Zl visible

    // --- GEMM2: M += Z^T K, quadrant (dq,eq), 8 MFMA into persistent acc ---
    {
      short8 kfr[2];
      kfr[0] = *(const short8*)&Kts[eq * 32 + 0  + ml][kq * 8];
      kfr[1] = *(const short8*)&Kts[eq * 32 + 16 + ml][kq * 8];
#pragma unroll
      for (int hl = 0; hl < 2; ++hl) {
#pragma unroll
        for (int dt = 0; dt < 2; ++dt) {
          short8 afr = hl ? *(const short8*)&Zl[dq * 32 + dt * 16 + ml][kq * 8]
                          : *(const short8*)&Zh[dq * 32 + dt * 16 + ml][kq * 8];
          mAcc[dt][0] = __builtin_amdgcn_mfma_f32_16x16x32_bf16(afr, kfr[0], mAcc[dt][0], 0, 0, 0);
          mAcc[dt][1] = __builtin_amdgcn_mfma_f32_16x16x32_bf16(afr, kfr[1], mAcc[dt][1], 0, 0, 0);
        }
      }
#pragma unroll
      for (int dt = 0; dt < 2; ++dt)
#pragma unroll
        for (int et = 0; et < 2; ++et)
#pragma unroll
          for (int r = 0; r < 4; ++r) {
            int d = dq * 32 + dt * 16 + kq * 4 + r;
            int ec = eq * 32 + et * 16 + ml;
            float mv = mAcc[dt][et][r];
            unsigned short mh = f2bf(mv);
            Mh[d][ec] = mh;
            Ml[d][ec] = f2bf(mv - bf2f(mh));
          }
    }
    __syncthreads();   // GEMM2 LDS reads done; Mh/Ml written

    // --- commit next chunk's staged regs into LDS ---
    *(uint4*)&Gb[grow][gc8]      = sq;
    *(uint4*)&Gb[32 + grow][gc8] = sw;
    *(uint4*)&Ub[grow][gc8]      = su;
    *(uint4*)&Kts[ke][kt8]       = sk;
  }
}

// ---------------- gate*o -> bf16 ----------------
__global__ __launch_bounds__(256) void gate_mul_kernel(
    const unsigned short* __restrict__ gsig, const float* __restrict__ o,
    unsigned short* __restrict__ out, int n4)
{
  int i = blockIdx.x * blockDim.x + threadIdx.x;
  int stride = gridDim.x * blockDim.x;
  const ushort4* g4 = (const ushort4*)gsig;
  const float4* o4 = (const float4*)o;
  ushort4* out4 = (ushort4*)out;
  for (; i < n4; i += stride) {
    ushort4 gv = g4[i];
    float4 ov = o4[i];
    ushort4 u;
    u.x = f2bf(bf2f(gv.x) * ov.x);
    u.y = f2bf(bf2f(gv.y) * ov.y);
    u.z = f2bf(bf2f(gv.z) * ov.z);
    u.w = f2bf(bf2f(gv.w) * ov.w);
    out4[i] = u;
  }
}

extern "C" void kernel_launch(void* const* d_in, const int* in_sizes, int n_in,
                              void* d_out, int out_size, void* d_ws, size_t ws_size,
                              hipStream_t stream) {
  const float* x     = (const float*)d_in[0];
  const float* Wq    = (const float*)d_in[1];
  const float* Wk    = (const float*)d_in[2];
  const float* Wv    = (const float*)d_in[3];
  const float* Wbeta = (const float*)d_in[4];
  const float* bbeta = (const float*)d_in[5];
  const float* Wgate = (const float*)d_in[6];
  const float* Wo    = (const float*)d_in[7];
  float* out = (float*)d_out;

  char* ws = (char*)d_ws;
  size_t off = 0;
  auto alloc = [&](size_t bytes) -> char* {
    char* p = ws + off;
    off += (bytes + 255) & ~(size_t)255;
    return p;
  };
  unsigned short* xb  = (unsigned short*)alloc((size_t)NTOK * Cz * 2);
  unsigned short* Wqb = (unsigned short*)alloc((size_t)Cz * Cz * 2);
  unsigned short* Wkb = (unsigned short*)alloc((size_t)Cz * Cz * 2);
  unsigned short* Wvb = (unsigned short*)alloc((size_t)Cz * Cz * 2);
  unsigned short* Wgb = (unsigned short*)alloc((size_t)Cz * Cz * 2);
  unsigned short* Wob = (unsigned short*)alloc((size_t)Cz * Cz * 2);
  unsigned short* qb  = (unsigned short*)alloc((size_t)NTOK * Cz * 2);   // bf16 q (l2normed)
  unsigned short* kb  = (unsigned short*)alloc((size_t)NTOK * Cz * 2);
  unsigned short* vb  = (unsigned short*)alloc((size_t)NTOK * Cz * 2);
  unsigned short* gb  = (unsigned short*)alloc((size_t)NTOK * Cz * 2);   // sigmoid(gate) bf16
  float* of    = (float*)alloc((size_t)NTOK * Cz * 4);
  float* betaf = (float*)alloc((size_t)NTOK * Hz * 4);
  unsigned short* qtb  = (unsigned short*)alloc((size_t)64 * NCH * 2048 * 2);
  unsigned short* wbuf = (unsigned short*)alloc((size_t)64 * NCH * 2048 * 2);
  unsigned short* ubuf = (unsigned short*)alloc((size_t)64 * NCH * 2048 * 2);
  unsigned short* ktb  = (unsigned short*)alloc((size_t)64 * NCH * 2048 * 2);
  unsigned short* ab = xb;  // reuse xb after projection GEMMs

  const int n4x = NTOK * Cz / 4;
  const int n4w = Cz * Cz / 4;

  cvt_bf16_kernel<<<dim3(1024), dim3(256), 0, stream>>>(x, xb, n4x);
  cvt_w5_kernel<<<dim3(n4w / 256, 5), dim3(256), 0, stream>>>(
      Wq, Wk, Wv, Wgate, Wo, Wqb, Wkb, Wvb, Wgb, Wob, n4w);

  // fused q,k,v,gate projections -> bf16; q,k l2norm epilogue, gate sigmoid
  gemm_bt_kernel<<<dim3(Cz / 128, NTOK / 128, 4), dim3(256), 0, stream>>>(
      xb, Wqb, Wkb, Wvb, Wgb, qb, kb, vb, gb, NTOK, Cz, Cz, 3, 3, 1);

  beta_kernel<<<dim3(NTOK), dim3(256), 0, stream>>>(x, Wbeta, bbeta, betaf);

  deltachunk_phase1<<<dim3(64 * NCH), dim3(256), 0, stream>>>(
      qb, kb, vb, betaf, of, qtb, wbuf, ubuf, ktb);
  deltachunk_phase2<<<dim3(Bz * Hz), dim3(256), 0, stream>>>(qtb, wbuf, ubuf, ktb, of);

  gate_mul_kernel<<<dim3(1024), dim3(256), 0, stream>>>(gb, of, ab, n4x);

  // out = (gate*o) @ Wo^T  (fp32 output)
  gemm_bt_kernel<<<dim3(Cz / 128, NTOK / 128, 1), dim3(256), 0, stream>>>(
      ab, Wob, Wob, Wob, Wob, out, out, out, out, NTOK, Cz, Cz, -1, 0, 0);
}